// Round 7
// baseline (2333.801 us; speedup 1.0000x reference)
//
#include <hip/hip_runtime.h>

#define NN 100000
#define NE 1250000
#define NR 8
#define DD 64
#define TILE 128
#define NTILES 782                 // ceil(100000/128)
#define NBUCKETS (NR * NTILES)     // 6256 dst-buckets (rel, dst-tile)
#define EPSB 1e-5f

typedef unsigned short u16;
typedef unsigned int u32;

static __device__ __forceinline__ float b2f_lo(u32 v) { return __uint_as_float(v << 16); }
static __device__ __forceinline__ float b2f_hi(u32 v) { return __uint_as_float(v & 0xffff0000u); }
static __device__ __forceinline__ u16 f2b(float f) {
    u32 u = __float_as_uint(f);
    u += 0x7fffu + ((u >> 16) & 1u);   // round-to-nearest-even
    return (u16)(u >> 16);
}
static __device__ __forceinline__ u32 pk(float a, float b) {
    return (u32)f2b(a) | ((u32)f2b(b) << 16);
}

// ---------------- fp32 -> bf16 copy of x ----------------

__global__ void cvt_kernel(const float* __restrict__ in, u16* __restrict__ outb) {
    int i = blockIdx.x * 256 + threadIdx.x;
    if (i < NN * DD / 8) {
        float4 a = *(const float4*)&in[i * 8];
        float4 b = *(const float4*)&in[i * 8 + 4];
        uint4 o;
        o.x = pk(a.x, a.y); o.y = pk(a.z, a.w);
        o.z = pk(b.x, b.y); o.w = pk(b.z, b.w);
        *(uint4*)&outb[i * 8] = o;
    }
}

// ---------------- CSR builds (once per call) ----------------
// dst-CSR: bucket b = r*NTILES + (dst>>7); ep[pos] = src<<8 | (dst&127)
// src-CSR: bucket s = src>>7;            ep2[..] = pos<<7 | (src&127)

__global__ void count_kernel(const int* __restrict__ dst,
                             const int* __restrict__ et,
                             int* __restrict__ cnt) {
    int i = blockIdx.x * 256 + threadIdx.x;
    if (i < NE) atomicAdd(&cnt[et[i] * NTILES + (dst[i] >> 7)], 1);
}

__global__ void scan_kernel(const int* __restrict__ cnt, int* __restrict__ off, int n) {
    __shared__ int ts[1024];
    int t = threadIdx.x;
    int v[8];
    int s = 0;
#pragma unroll
    for (int j = 0; j < 8; j++) {
        int idx = t * 8 + j;
        int c = (idx < n) ? cnt[idx] : 0;
        v[j] = s;
        s += c;
    }
    ts[t] = s;
    __syncthreads();
    for (int d = 1; d < 1024; d <<= 1) {
        int add = (t >= d) ? ts[t - d] : 0;
        __syncthreads();
        ts[t] += add;
        __syncthreads();
    }
    int base = (t > 0) ? ts[t - 1] : 0;
#pragma unroll
    for (int j = 0; j < 8; j++) {
        int idx = t * 8 + j;
        if (idx < n) off[idx] = base + v[j];
    }
    if (t == 1023) off[n] = ts[1023];
}

__global__ void fill_kernel(const int* __restrict__ src, const int* __restrict__ dst,
                            const int* __restrict__ et, const int* __restrict__ off,
                            int* __restrict__ cursor, int* __restrict__ ep) {
    int i = blockIdx.x * 256 + threadIdx.x;
    if (i < NE) {
        int d = dst[i];
        int b = et[i] * NTILES + (d >> 7);
        int pos = off[b] + atomicAdd(&cursor[b], 1);
        ep[pos] = (src[i] << 8) | (d & 127);
    }
}

__global__ void count2_kernel(const int* __restrict__ ep, int* __restrict__ cnt2) {
    int i = blockIdx.x * 256 + threadIdx.x;
    if (i < NE) atomicAdd(&cnt2[ep[i] >> 15], 1);
}

__global__ void fill2_kernel(const int* __restrict__ ep, const int* __restrict__ off2,
                             int* __restrict__ cursor2, int* __restrict__ ep2) {
    int i = blockIdx.x * 256 + threadIdx.x;
    if (i < NE) {
        int p = ep[i];
        int s = p >> 15;
        ep2[off2[s] + atomicAdd(&cursor2[s], 1)] = (i << 7) | ((p >> 8) & 127);
    }
}

// ---------------- phaseA: x src-tile in LDS -> scatter full-line writes to gx ----------------

__launch_bounds__(256, 8)
__global__ void phaseA_kernel(const u16* __restrict__ xb,
                              const int* __restrict__ ep2, const int* __restrict__ off2,
                              const int* __restrict__ off,
                              u16* __restrict__ gx, int rpp, int g) {
    __shared__ __align__(16) uint4 xs4[TILE][8];   // 16 KB: one x src-tile, raw bf16
    int s = blockIdx.x;
    int n0 = s * TILE;
    int tid = threadIdx.x;
    for (int idx = tid; idx < TILE * 8; idx += 256) {
        int row = idx >> 3, q = idx & 7;
        int n = n0 + row;
        if (n < NN) xs4[row][q] = *(const uint4*)&xb[(size_t)n * DD + q * 8];
    }
    int passbase = off[g * rpp * NTILES];
    int passend  = off[(g + 1) * rpp * NTILES];
    int e0 = off2[s], e1 = off2[s + 1];
    __syncthreads();
    int q = tid & 7;
    for (int w = tid >> 3; w < e1 - e0; w += 32) {
        int pe = ep2[e0 + w];                 // sequential read (8 lanes broadcast)
        int pos = pe >> 7;
        if (pos >= passbase && pos < passend) {
            uint4 v = xs4[pe & 127][q];
            *(uint4*)&gx[(size_t)(pos - passbase) * DD + q * 8] = v;  // full 128B line, fire-and-forget
        }
    }
}

// ---------------- mm1: sequential gx segment -> LDS-accumulate -> z = h@W1+b1, BN stats ----------------

__launch_bounds__(256, 3)
__global__ void mm1_kernel(const u16* __restrict__ xb, const u16* __restrict__ gx,
                           const int* __restrict__ ep, const int* __restrict__ off,
                           const float* __restrict__ W1l, const float* __restrict__ b1l,
                           const float* __restrict__ rW1l, const float* __restrict__ rb1l,
                           u16* __restrict__ zb, float* __restrict__ stats,
                           int rpp, int g) {
    __shared__ __align__(16) float hs[TILE + 1][68];   // row 128 = pad-lane scratch
    __shared__ __align__(16) float Ws[DD][DD];
    __shared__ float red[2 * DD];
    int r = g * rpp + blockIdx.y;          // == NR -> root path
    bool root = (r == NR);
    int n0 = blockIdx.x * TILE;
    int tid = threadIdx.x;

    const float* W = root ? rW1l : (W1l + (size_t)r * DD * DD);
    for (int idx = tid; idx < DD * DD; idx += 256)
        ((float*)Ws)[idx] = W[idx];

    if (!root) {
        for (int idx = tid; idx < (TILE + 1) * 68; idx += 256)
            ((float*)hs)[idx] = 0.f;
        __syncthreads();
        int b = r * NTILES + blockIdx.x;
        int e0 = off[b], e1 = off[b + 1];
        int passbase = off[g * rpp * NTILES];
        int m = e1 - e0;
        int mp = (m + 31) & ~31;
        int c0 = (tid & 7) * 8;
        for (int w = tid >> 3; w < mp; w += 32) {
            bool real = w < m;
            int pos = e0 + (real ? w : m - 1);
            int slot = real ? (ep[pos] & 127) : 128;
            uint4 v = *(const uint4*)&gx[(size_t)(pos - passbase) * DD + c0];  // sequential coalesced
            atomicAdd(&hs[slot][c0 + 0], b2f_lo(v.x));
            atomicAdd(&hs[slot][c0 + 1], b2f_hi(v.x));
            atomicAdd(&hs[slot][c0 + 2], b2f_lo(v.y));
            atomicAdd(&hs[slot][c0 + 3], b2f_hi(v.y));
            atomicAdd(&hs[slot][c0 + 4], b2f_lo(v.z));
            atomicAdd(&hs[slot][c0 + 5], b2f_hi(v.z));
            atomicAdd(&hs[slot][c0 + 6], b2f_lo(v.w));
            atomicAdd(&hs[slot][c0 + 7], b2f_hi(v.w));
        }
    } else {
        for (int c = tid; c < TILE * 8; c += 256) {
            int row = c >> 3, c0 = (c & 7) * 8;
            int n = n0 + row;
            uint4 vv = make_uint4(0, 0, 0, 0);
            if (n < NN) vv = *(const uint4*)&xb[(size_t)n * DD + c0];
            float4 A = make_float4(b2f_lo(vv.x), b2f_hi(vv.x), b2f_lo(vv.y), b2f_hi(vv.y));
            float4 B = make_float4(b2f_lo(vv.z), b2f_hi(vv.z), b2f_lo(vv.w), b2f_hi(vv.w));
            *(float4*)&hs[row][c0]     = A;
            *(float4*)&hs[row][c0 + 4] = B;
        }
    }
    __syncthreads();

    int tn = tid >> 3;
    int d0 = (tid & 7) * 8;

    float acc[4][8];
#pragma unroll
    for (int j = 0; j < 4; j++)
#pragma unroll
        for (int m2 = 0; m2 < 8; m2++) acc[j][m2] = 0.f;

#pragma unroll 4
    for (int kk = 0; kk < DD; kk += 4) {
        float hreg[4][4];
#pragma unroll
        for (int j = 0; j < 4; j++) {
            float4 t4 = *(const float4*)&hs[tn + 32 * j][kk];
            hreg[j][0] = t4.x; hreg[j][1] = t4.y; hreg[j][2] = t4.z; hreg[j][3] = t4.w;
        }
#pragma unroll
        for (int c = 0; c < 4; c++) {
            float4 wa = *(const float4*)&Ws[kk + c][d0];
            float4 wb = *(const float4*)&Ws[kk + c][d0 + 4];
            float w8[8] = {wa.x, wa.y, wa.z, wa.w, wb.x, wb.y, wb.z, wb.w};
#pragma unroll
            for (int j = 0; j < 4; j++)
#pragma unroll
                for (int m2 = 0; m2 < 8; m2++)
                    acc[j][m2] = fmaf(hreg[j][c], w8[m2], acc[j][m2]);
        }
    }

    const float* bvec = root ? rb1l : (b1l + r * DD);
    float bv[8];
#pragma unroll
    for (int m2 = 0; m2 < 8; m2++) bv[m2] = bvec[d0 + m2];

    u16* zout = zb + (size_t)r * NN * DD;
    float s1[8], s2[8];
#pragma unroll
    for (int m2 = 0; m2 < 8; m2++) { s1[m2] = 0.f; s2[m2] = 0.f; }

#pragma unroll
    for (int j = 0; j < 4; j++) {
        int n = n0 + tn + 32 * j;
        if (n < NN) {
            float vv[8];
#pragma unroll
            for (int m2 = 0; m2 < 8; m2++) {
                float v = acc[j][m2] + bv[m2];
                vv[m2] = v;
                s1[m2] += v;
                s2[m2] += v * v;
            }
            uint4 o;
            o.x = pk(vv[0], vv[1]); o.y = pk(vv[2], vv[3]);
            o.z = pk(vv[4], vv[5]); o.w = pk(vv[6], vv[7]);
            *(uint4*)&zout[(size_t)n * DD + d0] = o;
        }
    }

    if (tid < 128) red[tid] = 0.f;
    __syncthreads();
#pragma unroll
    for (int m2 = 0; m2 < 8; m2++) {
        float a = s1[m2], bq = s2[m2];
        a += __shfl_xor(a, 8);  bq += __shfl_xor(bq, 8);
        a += __shfl_xor(a, 16); bq += __shfl_xor(bq, 16);
        a += __shfl_xor(a, 32); bq += __shfl_xor(bq, 32);
        if ((tid & 63) < 8) {
            atomicAdd(&red[d0 + m2], a);
            atomicAdd(&red[64 + d0 + m2], bq);
        }
    }
    __syncthreads();
    if (tid < 64) {
        atomicAdd(&stats[r * DD + tid], red[tid]);
        atomicAdd(&stats[576 + r * DD + tid], red[64 + tid]);
    }
}

// ---------------- finalize: BN affine + fused const bias ----------------

__global__ void finalize_kernel(const float* __restrict__ stats,
                                const float* __restrict__ g1l, const float* __restrict__ be1l,
                                const float* __restrict__ rg1l, const float* __restrict__ rbe1l,
                                const float* __restrict__ b2l, const float* __restrict__ rb2l,
                                const float* __restrict__ biasl,
                                float* __restrict__ affine, float* __restrict__ constd) {
    int t = threadIdx.x;
    if (t < 576) {
        int r = t >> 6, d = t & 63;
        float mean = stats[t] * (1.f / NN);
        float var = fmaxf(stats[576 + t] * (1.f / NN) - mean * mean, 0.f);
        float g  = (r < NR) ? g1l[r * DD + d]  : rg1l[d];
        float be = (r < NR) ? be1l[r * DD + d] : rbe1l[d];
        float sc = g * rsqrtf(var + EPSB);
        affine[t] = sc;
        affine[576 + t] = be - mean * sc;
        if (r == 0) {
            float cd = rb2l[d] + biasl[d];
#pragma unroll
            for (int rr = 0; rr < NR; rr++) cd += b2l[rr * DD + d];
            constd[d] = cd;
        }
    }
}

// ---------------- pass2: out = sum_r relu(bn(z_r)) @ W2_r + const ----------------

__launch_bounds__(256, 3)
__global__ void pass2_kernel(const u16* __restrict__ zb,
                             const float* __restrict__ W2l, const float* __restrict__ rW2l,
                             const float* __restrict__ affine, const float* __restrict__ constd,
                             float* __restrict__ outf, u16* __restrict__ outb,
                             int emit_bf16_relu) {
    __shared__ __align__(16) float zs[TILE][68];
    __shared__ __align__(16) float W2s[DD][DD];
    int n0 = blockIdx.x * TILE;
    int tid = threadIdx.x;
    int tn = tid >> 3;
    int d0 = (tid & 7) * 8;
    int srow = tid >> 3;
    int sc0 = (tid & 7) * 8;

    float acc[4][8];
#pragma unroll
    for (int j = 0; j < 4; j++)
#pragma unroll
        for (int m = 0; m < 8; m++) acc[j][m] = 0.f;

    uint4 pre[4];
    {
        const u16* zp = zb;
#pragma unroll
        for (int q = 0; q < 4; q++) {
            int n = n0 + srow + 32 * q;
            pre[q] = (n < NN) ? *(const uint4*)&zp[(size_t)n * DD + sc0]
                              : make_uint4(0, 0, 0, 0);
        }
    }

    for (int r = 0; r < 9; r++) {
        float4 aLo = *(const float4*)&affine[r * DD + sc0];
        float4 aHi = *(const float4*)&affine[r * DD + sc0 + 4];
        float4 cLo = *(const float4*)&affine[576 + r * DD + sc0];
        float4 cHi = *(const float4*)&affine[576 + r * DD + sc0 + 4];
        __syncthreads();
#pragma unroll
        for (int q = 0; q < 4; q++) {
            uint4 vv = pre[q];
            float4 A = make_float4(b2f_lo(vv.x), b2f_hi(vv.x), b2f_lo(vv.y), b2f_hi(vv.y));
            float4 B = make_float4(b2f_lo(vv.z), b2f_hi(vv.z), b2f_lo(vv.w), b2f_hi(vv.w));
            A.x = fmaxf(fmaf(A.x, aLo.x, cLo.x), 0.f);
            A.y = fmaxf(fmaf(A.y, aLo.y, cLo.y), 0.f);
            A.z = fmaxf(fmaf(A.z, aLo.z, cLo.z), 0.f);
            A.w = fmaxf(fmaf(A.w, aLo.w, cLo.w), 0.f);
            B.x = fmaxf(fmaf(B.x, aHi.x, cHi.x), 0.f);
            B.y = fmaxf(fmaf(B.y, aHi.y, cHi.y), 0.f);
            B.z = fmaxf(fmaf(B.z, aHi.z, cHi.z), 0.f);
            B.w = fmaxf(fmaf(B.w, aHi.w, cHi.w), 0.f);
            *(float4*)&zs[srow + 32 * q][sc0]     = A;
            *(float4*)&zs[srow + 32 * q][sc0 + 4] = B;
        }
        const float* W = (r < NR) ? (W2l + (size_t)r * DD * DD) : rW2l;
        for (int idx = tid; idx < DD * DD; idx += 256)
            ((float*)W2s)[idx] = W[idx];
        __syncthreads();
        if (r + 1 < 9) {
            const u16* zp = zb + (size_t)(r + 1) * NN * DD;
#pragma unroll
            for (int q = 0; q < 4; q++) {
                int n = n0 + srow + 32 * q;
                pre[q] = (n < NN) ? *(const uint4*)&zp[(size_t)n * DD + sc0]
                                  : make_uint4(0, 0, 0, 0);
            }
        }

#pragma unroll 4
        for (int kk = 0; kk < DD; kk += 4) {
            float hreg[4][4];
#pragma unroll
            for (int j = 0; j < 4; j++) {
                float4 t4 = *(const float4*)&zs[tn + 32 * j][kk];
                hreg[j][0] = t4.x; hreg[j][1] = t4.y; hreg[j][2] = t4.z; hreg[j][3] = t4.w;
            }
#pragma unroll
            for (int c = 0; c < 4; c++) {
                float4 wa = *(const float4*)&W2s[kk + c][d0];
                float4 wb = *(const float4*)&W2s[kk + c][d0 + 4];
                float w8[8] = {wa.x, wa.y, wa.z, wa.w, wb.x, wb.y, wb.z, wb.w};
#pragma unroll
                for (int j = 0; j < 4; j++)
#pragma unroll
                    for (int m = 0; m < 8; m++)
                        acc[j][m] = fmaf(hreg[j][c], w8[m], acc[j][m]);
            }
        }
    }

    float cd[8];
#pragma unroll
    for (int m = 0; m < 8; m++) cd[m] = constd[d0 + m];

#pragma unroll
    for (int j = 0; j < 4; j++) {
        int n = n0 + tn + 32 * j;
        if (n < NN) {
            float vv[8];
#pragma unroll
            for (int m = 0; m < 8; m++) vv[m] = acc[j][m] + cd[m];
            if (emit_bf16_relu) {
#pragma unroll
                for (int m = 0; m < 8; m++) vv[m] = fmaxf(vv[m], 0.f);
                uint4 o;
                o.x = pk(vv[0], vv[1]); o.y = pk(vv[2], vv[3]);
                o.z = pk(vv[4], vv[5]); o.w = pk(vv[6], vv[7]);
                *(uint4*)&outb[(size_t)n * DD + d0] = o;
            } else {
                *(float4*)&outf[(size_t)n * DD + d0]     = make_float4(vv[0], vv[1], vv[2], vv[3]);
                *(float4*)&outf[(size_t)n * DD + d0 + 4] = make_float4(vv[4], vv[5], vv[6], vv[7]);
            }
        }
    }
}

// ---------------- host ----------------

extern "C" void kernel_launch(void* const* d_in, const int* in_sizes, int n_in,
                              void* d_out, int out_size, void* d_ws, size_t ws_size,
                              hipStream_t stream) {
    (void)in_sizes; (void)n_in; (void)out_size;

    const float* x0   = (const float*)d_in[0];
    const int*   ei   = (const int*)d_in[1];
    const int*   et   = (const int*)d_in[2];
    const float* W1   = (const float*)d_in[3];
    const float* b1   = (const float*)d_in[4];
    const float* g1   = (const float*)d_in[5];
    const float* be1  = (const float*)d_in[6];
    const float* W2   = (const float*)d_in[7];
    const float* b2   = (const float*)d_in[8];
    const float* rW1  = (const float*)d_in[9];
    const float* rb1  = (const float*)d_in[10];
    const float* rg1  = (const float*)d_in[11];
    const float* rbe1 = (const float*)d_in[12];
    const float* rW2  = (const float*)d_in[13];
    const float* rb2  = (const float*)d_in[14];
    const float* bias = (const float*)d_in[15];
    float* out = (float*)d_out;

    // pick relations-per-pass to fit ws (gx sized for the largest pass + big slack)
    size_t zelems = (size_t)9 * NN * DD;
    size_t base16 = (zelems + (size_t)NN * DD) * 2;          // zb + xb bytes
    size_t fixed4 = ((size_t)3 * NBUCKETS + 1 + 3 * NTILES + 1
                   + 2 * (size_t)NE + 1152 + 1152 + 64 + 64) * 4;
    int rpp = 0;
    size_t gxrows = 0;
    const int cands[3] = {4, 2, 1};
    for (int ci = 0; ci < 3; ci++) {
        int c = cands[ci];
        size_t rows = (size_t)c * (NE / NR) + (c == 1 ? 8000 : 60000);
        if (base16 + rows * 128 + fixed4 <= ws_size) { rpp = c; gxrows = rows; break; }
    }
    if (!rpp) return;
    int npass = NR / rpp;

    char* ws = (char*)d_ws;
    u16* zb = (u16*)ws;                               // 9*NN*DD
    u16* xb = zb + zelems;                            // NN*DD (shared across layers)
    u16* gx = xb + (size_t)NN * DD;                   // gxrows*64
    float* stats  = (float*)(gx + gxrows * DD);       // 1152
    float* affine = stats + 1152;                     // 1152
    float* constd = affine + 1152;                    // 64
    int* cnt     = (int*)(constd + 64);               // NBUCKETS
    int* cursor  = cnt + NBUCKETS;                    // NBUCKETS
    int* cnt2    = cursor + NBUCKETS;                 // NTILES
    int* cursor2 = cnt2 + NTILES;                     // NTILES
    int* off     = cursor2 + NTILES;                  // NBUCKETS+1
    int* off2    = off + NBUCKETS + 1;                // NTILES+1
    int* ep      = off2 + NTILES + 1;                 // NE
    int* ep2     = ep + NE;                           // NE

    cvt_kernel<<<(NN * DD / 8 + 255) / 256, 256, 0, stream>>>(x0, xb);
    hipMemsetAsync(cnt, 0, sizeof(int) * (2 * NBUCKETS + 2 * NTILES), stream);
    count_kernel<<<(NE + 255) / 256, 256, 0, stream>>>(ei + NE, et, cnt);
    scan_kernel<<<1, 1024, 0, stream>>>(cnt, off, NBUCKETS);
    fill_kernel<<<(NE + 255) / 256, 256, 0, stream>>>(ei, ei + NE, et, off, cursor, ep);
    count2_kernel<<<(NE + 255) / 256, 256, 0, stream>>>(ep, cnt2);
    scan_kernel<<<1, 1024, 0, stream>>>(cnt2, off2, NTILES);
    fill2_kernel<<<(NE + 255) / 256, 256, 0, stream>>>(ep, off2, cursor2, ep2);

    for (int i = 0; i < 2; i++) {
        hipMemsetAsync(stats, 0, sizeof(float) * 1152, stream);
        for (int g = 0; g < npass; g++) {
            phaseA_kernel<<<NTILES, 256, 0, stream>>>(xb, ep2, off2, off, gx, rpp, g);
            mm1_kernel<<<dim3(NTILES, rpp + (g == npass - 1 ? 1 : 0)), 256, 0, stream>>>(
                xb, gx, ep, off,
                W1 + (size_t)i * NR * DD * DD, b1 + (size_t)i * NR * DD,
                rW1 + (size_t)i * DD * DD, rb1 + (size_t)i * DD,
                zb, stats, rpp, g);
        }
        finalize_kernel<<<1, 576, 0, stream>>>(
            stats,
            g1 + (size_t)i * NR * DD, be1 + (size_t)i * NR * DD,
            rg1 + (size_t)i * DD, rbe1 + (size_t)i * DD,
            b2 + (size_t)i * NR * DD, rb2 + (size_t)i * DD, bias + (size_t)i * DD,
            affine, constd);
        pass2_kernel<<<NTILES, 256, 0, stream>>>(
            zb, W2 + (size_t)i * NR * DD * DD, rW2 + (size_t)i * DD * DD,
            affine, constd, out, xb, (i == 0) ? 1 : 0);
    }
}

// Round 8
// 2265.871 us; speedup vs baseline: 1.0300x; 1.0300x over previous
//
#include <hip/hip_runtime.h>

#define NN 100000
#define NE 1250000
#define NR 8
#define DD 64
#define TILE 128
#define NTILES 782                 // ceil(100000/128)
#define NBUCKETS (NR * NTILES)     // 6256 dst-buckets (rel, dst-tile)
#define HSTR 129                   // hs column-major stride (col 128 = dummy)
#define XSTR 34                    // phaseA xs row stride in dwords
#define EPSB 1e-5f

typedef unsigned short u16;
typedef unsigned int u32;

static __device__ __forceinline__ float b2f_lo(u32 v) { return __uint_as_float(v << 16); }
static __device__ __forceinline__ float b2f_hi(u32 v) { return __uint_as_float(v & 0xffff0000u); }
static __device__ __forceinline__ u16 f2b(float f) {
    u32 u = __float_as_uint(f);
    u += 0x7fffu + ((u >> 16) & 1u);   // round-to-nearest-even
    return (u16)(u >> 16);
}
static __device__ __forceinline__ u32 pk(float a, float b) {
    return (u32)f2b(a) | ((u32)f2b(b) << 16);
}

// ---------------- fp32 -> bf16 copy of x ----------------

__global__ void cvt_kernel(const float* __restrict__ in, u16* __restrict__ outb) {
    int i = blockIdx.x * 256 + threadIdx.x;
    if (i < NN * DD / 8) {
        float4 a = *(const float4*)&in[i * 8];
        float4 b = *(const float4*)&in[i * 8 + 4];
        uint4 o;
        o.x = pk(a.x, a.y); o.y = pk(a.z, a.w);
        o.z = pk(b.x, b.y); o.w = pk(b.z, b.w);
        *(uint4*)&outb[i * 8] = o;
    }
}

// ---------------- CSR builds (once per call) ----------------

__global__ void count_kernel(const int* __restrict__ dst,
                             const int* __restrict__ et,
                             int* __restrict__ cnt) {
    int i = blockIdx.x * 256 + threadIdx.x;
    if (i < NE) atomicAdd(&cnt[et[i] * NTILES + (dst[i] >> 7)], 1);
}

__global__ void scan_kernel(const int* __restrict__ cnt, int* __restrict__ off, int n) {
    __shared__ int ts[1024];
    int t = threadIdx.x;
    int v[8];
    int s = 0;
#pragma unroll
    for (int j = 0; j < 8; j++) {
        int idx = t * 8 + j;
        int c = (idx < n) ? cnt[idx] : 0;
        v[j] = s;
        s += c;
    }
    ts[t] = s;
    __syncthreads();
    for (int d = 1; d < 1024; d <<= 1) {
        int add = (t >= d) ? ts[t - d] : 0;
        __syncthreads();
        ts[t] += add;
        __syncthreads();
    }
    int base = (t > 0) ? ts[t - 1] : 0;
#pragma unroll
    for (int j = 0; j < 8; j++) {
        int idx = t * 8 + j;
        if (idx < n) off[idx] = base + v[j];
    }
    if (t == 1023) off[n] = ts[1023];
}

__global__ void fill_kernel(const int* __restrict__ src, const int* __restrict__ dst,
                            const int* __restrict__ et, const int* __restrict__ off,
                            int* __restrict__ cursor, int* __restrict__ ep) {
    int i = blockIdx.x * 256 + threadIdx.x;
    if (i < NE) {
        int d = dst[i];
        int b = et[i] * NTILES + (d >> 7);
        int pos = off[b] + atomicAdd(&cursor[b], 1);
        ep[pos] = (src[i] << 8) | (d & 127);
    }
}

__global__ void count2_kernel(const int* __restrict__ ep, int* __restrict__ cnt2) {
    int i = blockIdx.x * 256 + threadIdx.x;
    if (i < NE) atomicAdd(&cnt2[ep[i] >> 15], 1);
}

__global__ void fill2_kernel(const int* __restrict__ ep, const int* __restrict__ off2,
                             int* __restrict__ cursor2, int* __restrict__ ep2) {
    int i = blockIdx.x * 256 + threadIdx.x;
    if (i < NE) {
        int p = ep[i];
        int s = p >> 15;
        ep2[off2[s] + atomicAdd(&cursor2[s], 1)] = (i << 7) | ((p >> 8) & 127);
    }
}

// ---------------- phaseA: x src-tile in LDS -> per-lane half-row scatter writes to gx ----------------

__launch_bounds__(256, 8)
__global__ void phaseA_kernel(const u16* __restrict__ xb,
                              const int* __restrict__ ep2, const int* __restrict__ off2,
                              const int* __restrict__ off,
                              u16* __restrict__ gx, int rpp, int g) {
    __shared__ u32 xs[TILE * XSTR];   // row stride 34 dwords (data in 0..31)
    int s = blockIdx.x;
    int n0 = s * TILE;
    int tid = threadIdx.x;
    for (int idx = tid; idx < TILE * 8; idx += 256) {
        int row = idx >> 3, q = idx & 7;
        int n = n0 + row;
        if (n < NN) {
            uint4 v = *(const uint4*)&xb[(size_t)n * DD + q * 8];
            u32* p = &xs[row * XSTR + q * 4];
            *(uint2*)(p)     = make_uint2(v.x, v.y);
            *(uint2*)(p + 2) = make_uint2(v.z, v.w);
        }
    }
    int passbase = off[g * rpp * NTILES];
    int passend  = off[(g + 1) * rpp * NTILES];
    int e0 = off2[s], e1 = off2[s + 1];
    int m = e1 - e0;
    __syncthreads();

    int half = tid & 1;           // lane owns a 64B half-row (one cache line)
    for (int w = tid >> 1; w < m; w += 128) {
        int pe = ep2[e0 + w];
        int pos = pe >> 7;
        if (pos >= passbase && pos < passend) {
            const u32* xrow = &xs[(pe & 127) * XSTR + half * 16];
            uint2 a0 = *(const uint2*)(xrow + 0);
            uint2 a1 = *(const uint2*)(xrow + 2);
            uint2 a2 = *(const uint2*)(xrow + 4);
            uint2 a3 = *(const uint2*)(xrow + 6);
            uint2 a4 = *(const uint2*)(xrow + 8);
            uint2 a5 = *(const uint2*)(xrow + 10);
            uint2 a6 = *(const uint2*)(xrow + 12);
            uint2 a7 = *(const uint2*)(xrow + 14);
            u16* orow = &gx[(size_t)(pos - passbase) * DD + half * 32];
            *(uint4*)(orow)      = make_uint4(a0.x, a0.y, a1.x, a1.y);
            *(uint4*)(orow + 8)  = make_uint4(a2.x, a2.y, a3.x, a3.y);
            *(uint4*)(orow + 16) = make_uint4(a4.x, a4.y, a5.x, a5.y);
            *(uint4*)(orow + 24) = make_uint4(a6.x, a6.y, a7.x, a7.y);
        }
    }
}

// ---------------- mm1: per-lane half-row gx read -> col-major LDS accumulate -> z=h@W1+b1, BN stats ----------------

__launch_bounds__(256, 3)
__global__ void mm1_kernel(const u16* __restrict__ xb, const u16* __restrict__ gx,
                           const int* __restrict__ ep, const int* __restrict__ off,
                           const float* __restrict__ W1l, const float* __restrict__ b1l,
                           const float* __restrict__ rW1l, const float* __restrict__ rb1l,
                           u16* __restrict__ zb, float* __restrict__ stats,
                           int rpp, int g) {
    __shared__ float hs[DD * HSTR];    // column-major: hs[k*129 + slot], slot 128 = dummy
    __shared__ __align__(16) float Ws[DD][DD];
    __shared__ float red[2 * DD];
    int r = g * rpp + blockIdx.y;          // == NR -> root path
    bool root = (r == NR);
    int n0 = blockIdx.x * TILE;
    int tid = threadIdx.x;

    const float* W = root ? rW1l : (W1l + (size_t)r * DD * DD);
    for (int idx = tid; idx < DD * DD; idx += 256)
        ((float*)Ws)[idx] = W[idx];

    if (!root) {
        for (int idx = tid; idx < DD * HSTR; idx += 256) hs[idx] = 0.f;
        __syncthreads();
        int b = r * NTILES + blockIdx.x;
        int e0 = off[b], e1 = off[b + 1];
        int passbase = off[g * rpp * NTILES];
        int m = e1 - e0;
        int half = tid & 1;                // lane owns 64B half-row: k = half*32 .. +31
        for (int w = tid >> 1; w < m; w += 128) {
            int pos = e0 + w;
            int slot = ep[pos] & 127;
            const u16* grow = &gx[(size_t)(pos - passbase) * DD + half * 32];
            uint4 v0 = *(const uint4*)(grow + 0);
            uint4 v1 = *(const uint4*)(grow + 8);
            uint4 v2 = *(const uint4*)(grow + 16);
            uint4 v3 = *(const uint4*)(grow + 24);
            float* basep = &hs[(size_t)(half * 32) * HSTR + slot];
#pragma unroll
            for (int q = 0; q < 4; q++) {
                uint4 v = (q == 0) ? v0 : (q == 1) ? v1 : (q == 2) ? v2 : v3;
                float* bq = basep + q * 8 * HSTR;
                atomicAdd(bq + 0 * HSTR, b2f_lo(v.x));
                atomicAdd(bq + 1 * HSTR, b2f_hi(v.x));
                atomicAdd(bq + 2 * HSTR, b2f_lo(v.y));
                atomicAdd(bq + 3 * HSTR, b2f_hi(v.y));
                atomicAdd(bq + 4 * HSTR, b2f_lo(v.z));
                atomicAdd(bq + 5 * HSTR, b2f_hi(v.z));
                atomicAdd(bq + 6 * HSTR, b2f_lo(v.w));
                atomicAdd(bq + 7 * HSTR, b2f_hi(v.w));
            }
        }
    } else {
        // root path: stage this x tile transposed into col-major hs
        for (int c = tid; c < TILE * 8; c += 256) {
            int row = c >> 3, c0 = (c & 7) * 8;
            int n = n0 + row;
            uint4 vv = make_uint4(0, 0, 0, 0);
            if (n < NN) vv = *(const uint4*)&xb[(size_t)n * DD + c0];
            hs[(c0 + 0) * HSTR + row] = b2f_lo(vv.x);
            hs[(c0 + 1) * HSTR + row] = b2f_hi(vv.x);
            hs[(c0 + 2) * HSTR + row] = b2f_lo(vv.y);
            hs[(c0 + 3) * HSTR + row] = b2f_hi(vv.y);
            hs[(c0 + 4) * HSTR + row] = b2f_lo(vv.z);
            hs[(c0 + 5) * HSTR + row] = b2f_hi(vv.z);
            hs[(c0 + 6) * HSTR + row] = b2f_lo(vv.w);
            hs[(c0 + 7) * HSTR + row] = b2f_hi(vv.w);
        }
    }
    __syncthreads();

    int tn = tid >> 3;
    int d0 = (tid & 7) * 8;

    float acc[4][8];
#pragma unroll
    for (int j = 0; j < 4; j++)
#pragma unroll
        for (int m2 = 0; m2 < 8; m2++) acc[j][m2] = 0.f;

#pragma unroll 4
    for (int kk = 0; kk < DD; kk += 4) {
        float hreg[4][4];
#pragma unroll
        for (int c = 0; c < 4; c++)
#pragma unroll
            for (int j = 0; j < 4; j++)
                hreg[j][c] = hs[(kk + c) * HSTR + tn + 32 * j];   // broadcast b32, conflict-free
#pragma unroll
        for (int c = 0; c < 4; c++) {
            float4 wa = *(const float4*)&Ws[kk + c][d0];
            float4 wb = *(const float4*)&Ws[kk + c][d0 + 4];
            float w8[8] = {wa.x, wa.y, wa.z, wa.w, wb.x, wb.y, wb.z, wb.w};
#pragma unroll
            for (int j = 0; j < 4; j++)
#pragma unroll
                for (int m2 = 0; m2 < 8; m2++)
                    acc[j][m2] = fmaf(hreg[j][c], w8[m2], acc[j][m2]);
        }
    }

    const float* bvec = root ? rb1l : (b1l + r * DD);
    float bv[8];
#pragma unroll
    for (int m2 = 0; m2 < 8; m2++) bv[m2] = bvec[d0 + m2];

    u16* zout = zb + (size_t)r * NN * DD;
    float s1[8], s2[8];
#pragma unroll
    for (int m2 = 0; m2 < 8; m2++) { s1[m2] = 0.f; s2[m2] = 0.f; }

#pragma unroll
    for (int j = 0; j < 4; j++) {
        int n = n0 + tn + 32 * j;
        if (n < NN) {
            float vv[8];
#pragma unroll
            for (int m2 = 0; m2 < 8; m2++) {
                float v = acc[j][m2] + bv[m2];
                vv[m2] = v;
                s1[m2] += v;
                s2[m2] += v * v;
            }
            uint4 o;
            o.x = pk(vv[0], vv[1]); o.y = pk(vv[2], vv[3]);
            o.z = pk(vv[4], vv[5]); o.w = pk(vv[6], vv[7]);
            *(uint4*)&zout[(size_t)n * DD + d0] = o;
        }
    }

    if (tid < 128) red[tid] = 0.f;
    __syncthreads();
#pragma unroll
    for (int m2 = 0; m2 < 8; m2++) {
        float a = s1[m2], bq = s2[m2];
        a += __shfl_xor(a, 8);  bq += __shfl_xor(bq, 8);
        a += __shfl_xor(a, 16); bq += __shfl_xor(bq, 16);
        a += __shfl_xor(a, 32); bq += __shfl_xor(bq, 32);
        if ((tid & 63) < 8) {
            atomicAdd(&red[d0 + m2], a);
            atomicAdd(&red[64 + d0 + m2], bq);
        }
    }
    __syncthreads();
    if (tid < 64) {
        atomicAdd(&stats[r * DD + tid], red[tid]);
        atomicAdd(&stats[576 + r * DD + tid], red[64 + tid]);
    }
}

// ---------------- finalize: BN affine + fused const bias ----------------

__global__ void finalize_kernel(const float* __restrict__ stats,
                                const float* __restrict__ g1l, const float* __restrict__ be1l,
                                const float* __restrict__ rg1l, const float* __restrict__ rbe1l,
                                const float* __restrict__ b2l, const float* __restrict__ rb2l,
                                const float* __restrict__ biasl,
                                float* __restrict__ affine, float* __restrict__ constd) {
    int t = threadIdx.x;
    if (t < 576) {
        int r = t >> 6, d = t & 63;
        float mean = stats[t] * (1.f / NN);
        float var = fmaxf(stats[576 + t] * (1.f / NN) - mean * mean, 0.f);
        float g  = (r < NR) ? g1l[r * DD + d]  : rg1l[d];
        float be = (r < NR) ? be1l[r * DD + d] : rbe1l[d];
        float sc = g * rsqrtf(var + EPSB);
        affine[t] = sc;
        affine[576 + t] = be - mean * sc;
        if (r == 0) {
            float cd = rb2l[d] + biasl[d];
#pragma unroll
            for (int rr = 0; rr < NR; rr++) cd += b2l[rr * DD + d];
            constd[d] = cd;
        }
    }
}

// ---------------- pass2: out = sum_r relu(bn(z_r)) @ W2_r + const ----------------

__launch_bounds__(256, 3)
__global__ void pass2_kernel(const u16* __restrict__ zb,
                             const float* __restrict__ W2l, const float* __restrict__ rW2l,
                             const float* __restrict__ affine, const float* __restrict__ constd,
                             float* __restrict__ outf, u16* __restrict__ outb,
                             int emit_bf16_relu) {
    __shared__ __align__(16) float zs[TILE][68];
    __shared__ __align__(16) float W2s[DD][DD];
    int n0 = blockIdx.x * TILE;
    int tid = threadIdx.x;
    int tn = tid >> 3;
    int d0 = (tid & 7) * 8;
    int srow = tid >> 3;
    int sc0 = (tid & 7) * 8;

    float acc[4][8];
#pragma unroll
    for (int j = 0; j < 4; j++)
#pragma unroll
        for (int m = 0; m < 8; m++) acc[j][m] = 0.f;

    uint4 pre[4];
    {
        const u16* zp = zb;
#pragma unroll
        for (int q = 0; q < 4; q++) {
            int n = n0 + srow + 32 * q;
            pre[q] = (n < NN) ? *(const uint4*)&zp[(size_t)n * DD + sc0]
                              : make_uint4(0, 0, 0, 0);
        }
    }

    for (int r = 0; r < 9; r++) {
        float4 aLo = *(const float4*)&affine[r * DD + sc0];
        float4 aHi = *(const float4*)&affine[r * DD + sc0 + 4];
        float4 cLo = *(const float4*)&affine[576 + r * DD + sc0];
        float4 cHi = *(const float4*)&affine[576 + r * DD + sc0 + 4];
        __syncthreads();
#pragma unroll
        for (int q = 0; q < 4; q++) {
            uint4 vv = pre[q];
            float4 A = make_float4(b2f_lo(vv.x), b2f_hi(vv.x), b2f_lo(vv.y), b2f_hi(vv.y));
            float4 B = make_float4(b2f_lo(vv.z), b2f_hi(vv.z), b2f_lo(vv.w), b2f_hi(vv.w));
            A.x = fmaxf(fmaf(A.x, aLo.x, cLo.x), 0.f);
            A.y = fmaxf(fmaf(A.y, aLo.y, cLo.y), 0.f);
            A.z = fmaxf(fmaf(A.z, aLo.z, cLo.z), 0.f);
            A.w = fmaxf(fmaf(A.w, aLo.w, cLo.w), 0.f);
            B.x = fmaxf(fmaf(B.x, aHi.x, cHi.x), 0.f);
            B.y = fmaxf(fmaf(B.y, aHi.y, cHi.y), 0.f);
            B.z = fmaxf(fmaf(B.z, aHi.z, cHi.z), 0.f);
            B.w = fmaxf(fmaf(B.w, aHi.w, cHi.w), 0.f);
            *(float4*)&zs[srow + 32 * q][sc0]     = A;
            *(float4*)&zs[srow + 32 * q][sc0 + 4] = B;
        }
        const float* W = (r < NR) ? (W2l + (size_t)r * DD * DD) : rW2l;
        for (int idx = tid; idx < DD * DD; idx += 256)
            ((float*)W2s)[idx] = W[idx];
        __syncthreads();
        if (r + 1 < 9) {
            const u16* zp = zb + (size_t)(r + 1) * NN * DD;
#pragma unroll
            for (int q = 0; q < 4; q++) {
                int n = n0 + srow + 32 * q;
                pre[q] = (n < NN) ? *(const uint4*)&zp[(size_t)n * DD + sc0]
                                  : make_uint4(0, 0, 0, 0);
            }
        }

#pragma unroll 4
        for (int kk = 0; kk < DD; kk += 4) {
            float hreg[4][4];
#pragma unroll
            for (int j = 0; j < 4; j++) {
                float4 t4 = *(const float4*)&zs[tn + 32 * j][kk];
                hreg[j][0] = t4.x; hreg[j][1] = t4.y; hreg[j][2] = t4.z; hreg[j][3] = t4.w;
            }
#pragma unroll
            for (int c = 0; c < 4; c++) {
                float4 wa = *(const float4*)&W2s[kk + c][d0];
                float4 wb = *(const float4*)&W2s[kk + c][d0 + 4];
                float w8[8] = {wa.x, wa.y, wa.z, wa.w, wb.x, wb.y, wb.z, wb.w};
#pragma unroll
                for (int j = 0; j < 4; j++)
#pragma unroll
                    for (int m = 0; m < 8; m++)
                        acc[j][m] = fmaf(hreg[j][c], w8[m], acc[j][m]);
            }
        }
    }

    float cd[8];
#pragma unroll
    for (int m = 0; m < 8; m++) cd[m] = constd[d0 + m];

#pragma unroll
    for (int j = 0; j < 4; j++) {
        int n = n0 + tn + 32 * j;
        if (n < NN) {
            float vv[8];
#pragma unroll
            for (int m = 0; m < 8; m++) vv[m] = acc[j][m] + cd[m];
            if (emit_bf16_relu) {
#pragma unroll
                for (int m = 0; m < 8; m++) vv[m] = fmaxf(vv[m], 0.f);
                uint4 o;
                o.x = pk(vv[0], vv[1]); o.y = pk(vv[2], vv[3]);
                o.z = pk(vv[4], vv[5]); o.w = pk(vv[6], vv[7]);
                *(uint4*)&outb[(size_t)n * DD + d0] = o;
            } else {
                *(float4*)&outf[(size_t)n * DD + d0]     = make_float4(vv[0], vv[1], vv[2], vv[3]);
                *(float4*)&outf[(size_t)n * DD + d0 + 4] = make_float4(vv[4], vv[5], vv[6], vv[7]);
            }
        }
    }
}

// ---------------- host ----------------

extern "C" void kernel_launch(void* const* d_in, const int* in_sizes, int n_in,
                              void* d_out, int out_size, void* d_ws, size_t ws_size,
                              hipStream_t stream) {
    (void)in_sizes; (void)n_in; (void)out_size;

    const float* x0   = (const float*)d_in[0];
    const int*   ei   = (const int*)d_in[1];
    const int*   et   = (const int*)d_in[2];
    const float* W1   = (const float*)d_in[3];
    const float* b1   = (const float*)d_in[4];
    const float* g1   = (const float*)d_in[5];
    const float* be1  = (const float*)d_in[6];
    const float* W2   = (const float*)d_in[7];
    const float* b2   = (const float*)d_in[8];
    const float* rW1  = (const float*)d_in[9];
    const float* rb1  = (const float*)d_in[10];
    const float* rg1  = (const float*)d_in[11];
    const float* rbe1 = (const float*)d_in[12];
    const float* rW2  = (const float*)d_in[13];
    const float* rb2  = (const float*)d_in[14];
    const float* bias = (const float*)d_in[15];
    float* out = (float*)d_out;

    size_t zelems = (size_t)9 * NN * DD;
    size_t base16 = (zelems + (size_t)NN * DD) * 2;          // zb + xb bytes
    size_t fixed4 = ((size_t)3 * NBUCKETS + 1 + 3 * NTILES + 1
                   + 2 * (size_t)NE + 1152 + 1152 + 64 + 64) * 4;
    int rpp = 0;
    size_t gxrows = 0;
    const int cands[3] = {4, 2, 1};
    for (int ci = 0; ci < 3; ci++) {
        int c = cands[ci];
        size_t rows = (size_t)c * (NE / NR) + (c == 1 ? 8000 : 60000);
        if (base16 + rows * 128 + fixed4 <= ws_size) { rpp = c; gxrows = rows; break; }
    }
    if (!rpp) return;
    int npass = NR / rpp;

    char* ws = (char*)d_ws;
    u16* zb = (u16*)ws;                               // 9*NN*DD
    u16* xb = zb + zelems;                            // NN*DD (shared across layers)
    u16* gx = xb + (size_t)NN * DD;                   // gxrows*64
    float* stats  = (float*)(gx + gxrows * DD);       // 1152
    float* affine = stats + 1152;                     // 1152
    float* constd = affine + 1152;                    // 64
    int* cnt     = (int*)(constd + 64);               // NBUCKETS
    int* cursor  = cnt + NBUCKETS;                    // NBUCKETS
    int* cnt2    = cursor + NBUCKETS;                 // NTILES
    int* cursor2 = cnt2 + NTILES;                     // NTILES
    int* off     = cursor2 + NTILES;                  // NBUCKETS+1
    int* off2    = off + NBUCKETS + 1;                // NTILES+1
    int* ep      = off2 + NTILES + 1;                 // NE
    int* ep2     = ep + NE;                           // NE

    cvt_kernel<<<(NN * DD / 8 + 255) / 256, 256, 0, stream>>>(x0, xb);
    hipMemsetAsync(cnt, 0, sizeof(int) * (2 * NBUCKETS + 2 * NTILES), stream);
    count_kernel<<<(NE + 255) / 256, 256, 0, stream>>>(ei + NE, et, cnt);
    scan_kernel<<<1, 1024, 0, stream>>>(cnt, off, NBUCKETS);
    fill_kernel<<<(NE + 255) / 256, 256, 0, stream>>>(ei, ei + NE, et, off, cursor, ep);
    count2_kernel<<<(NE + 255) / 256, 256, 0, stream>>>(ep, cnt2);
    scan_kernel<<<1, 1024, 0, stream>>>(cnt2, off2, NTILES);
    fill2_kernel<<<(NE + 255) / 256, 256, 0, stream>>>(ep, off2, cursor2, ep2);

    for (int i = 0; i < 2; i++) {
        hipMemsetAsync(stats, 0, sizeof(float) * 1152, stream);
        for (int g = 0; g < npass; g++) {
            phaseA_kernel<<<NTILES, 256, 0, stream>>>(xb, ep2, off2, off, gx, rpp, g);
            mm1_kernel<<<dim3(NTILES, rpp + (g == npass - 1 ? 1 : 0)), 256, 0, stream>>>(
                xb, gx, ep, off,
                W1 + (size_t)i * NR * DD * DD, b1 + (size_t)i * NR * DD,
                rW1 + (size_t)i * DD * DD, rb1 + (size_t)i * DD,
                zb, stats, rpp, g);
        }
        finalize_kernel<<<1, 576, 0, stream>>>(
            stats,
            g1 + (size_t)i * NR * DD, be1 + (size_t)i * NR * DD,
            rg1 + (size_t)i * DD, rbe1 + (size_t)i * DD,
            b2 + (size_t)i * NR * DD, rb2 + (size_t)i * DD, bias + (size_t)i * DD,
            affine, constd);
        pass2_kernel<<<NTILES, 256, 0, stream>>>(
            zb, W2 + (size_t)i * NR * DD * DD, rW2 + (size_t)i * DD * DD,
            affine, constd, out, xb, (i == 0) ? 1 : 0);
    }
}

// Round 9
// 762.753 us; speedup vs baseline: 3.0597x; 2.9706x over previous
//
#include <hip/hip_runtime.h>

#define NN 100000
#define NE 1250000
#define NR 8
#define DD 64
#define TILE 128
#define NTILES 782                 // ceil(100000/128)
#define NBUCKETS (NR * NTILES)     // 6256 dst-buckets (rel, dst-tile)
#define CAP 512                    // sorted edges per bucket (Poisson(200): overflow ~never)
#define HSTR 129                   // hs column-major stride
#define EPSB 1e-5f

typedef unsigned short u16;
typedef unsigned int u32;

static __device__ __forceinline__ float b2f_lo(u32 v) { return __uint_as_float(v << 16); }
static __device__ __forceinline__ float b2f_hi(u32 v) { return __uint_as_float(v & 0xffff0000u); }
static __device__ __forceinline__ u16 f2b(float f) {
    u32 u = __float_as_uint(f);
    u += 0x7fffu + ((u >> 16) & 1u);   // round-to-nearest-even
    return (u16)(u >> 16);
}
static __device__ __forceinline__ u32 pk(float a, float b) {
    return (u32)f2b(a) | ((u32)f2b(b) << 16);
}

// ---------------- fp32 -> bf16 copy of x ----------------

__global__ void cvt_kernel(const float* __restrict__ in, u16* __restrict__ outb) {
    int i = blockIdx.x * 256 + threadIdx.x;
    if (i < NN * DD / 8) {
        float4 a = *(const float4*)&in[i * 8];
        float4 b = *(const float4*)&in[i * 8 + 4];
        uint4 o;
        o.x = pk(a.x, a.y); o.y = pk(a.z, a.w);
        o.z = pk(b.x, b.y); o.w = pk(b.z, b.w);
        *(uint4*)&outb[i * 8] = o;
    }
}

// ---------------- dst-CSR build (once per call) ----------------

__global__ void count_kernel(const int* __restrict__ dst,
                             const int* __restrict__ et,
                             int* __restrict__ cnt) {
    int i = blockIdx.x * 256 + threadIdx.x;
    if (i < NE) atomicAdd(&cnt[et[i] * NTILES + (dst[i] >> 7)], 1);
}

__global__ void scan_kernel(const int* __restrict__ cnt, int* __restrict__ off, int n) {
    __shared__ int ts[1024];
    int t = threadIdx.x;
    int v[8];
    int s = 0;
#pragma unroll
    for (int j = 0; j < 8; j++) {
        int idx = t * 8 + j;
        int c = (idx < n) ? cnt[idx] : 0;
        v[j] = s;
        s += c;
    }
    ts[t] = s;
    __syncthreads();
    for (int d = 1; d < 1024; d <<= 1) {
        int add = (t >= d) ? ts[t - d] : 0;
        __syncthreads();
        ts[t] += add;
        __syncthreads();
    }
    int base = (t > 0) ? ts[t - 1] : 0;
#pragma unroll
    for (int j = 0; j < 8; j++) {
        int idx = t * 8 + j;
        if (idx < n) off[idx] = base + v[j];
    }
    if (t == 1023) off[n] = ts[1023];
}

__global__ void fill_kernel(const int* __restrict__ src, const int* __restrict__ dst,
                            const int* __restrict__ et, const int* __restrict__ off,
                            int* __restrict__ cursor, int* __restrict__ ep) {
    int i = blockIdx.x * 256 + threadIdx.x;
    if (i < NE) {
        int d = dst[i];
        int b = et[i] * NTILES + (d >> 7);
        int pos = off[b] + atomicAdd(&cursor[b], 1);
        ep[pos] = (src[i] << 8) | (d & 127);
    }
}

// ---------------- gemm1: counting-sort -> segmented register gather -> z = h@W1+b1, BN stats ----------------

__launch_bounds__(256, 3)
__global__ void gemm1_kernel(const u16* __restrict__ xb,
                             const int* __restrict__ ep, const int* __restrict__ off,
                             const float* __restrict__ W1l, const float* __restrict__ b1l,
                             const float* __restrict__ rW1l, const float* __restrict__ rb1l,
                             u16* __restrict__ zb, float* __restrict__ stats) {
    __shared__ float hs[DD * HSTR];                 // col-major: hs[k*HSTR + slot], 33 KB
    __shared__ __align__(16) u32 Wsb[DD * DD / 2];  // W as bf16 pairs, 8 KB
    __shared__ int seS[CAP], seD[CAP];
    __shared__ int shist[TILE], scur[TILE];
    __shared__ int soff[TILE + 1];
    __shared__ float red[2 * DD];
    int r = blockIdx.y;
    bool root = (r == NR);
    int n0 = blockIdx.x * TILE;
    int tid = threadIdx.x;

    const float* W = root ? rW1l : (W1l + (size_t)r * DD * DD);
    for (int i = tid; i < DD * DD / 2; i += 256) {
        float2 w2 = *(const float2*)&W[2 * i];
        Wsb[i] = pk(w2.x, w2.y);
    }

    if (!root) {
        int b = r * NTILES + blockIdx.x;
        int e0 = off[b], e1 = off[b + 1];
        int m = e1 - e0;
        int cnt = min(m, CAP);
        if (tid < TILE) shist[tid] = 0;
        __syncthreads();
        // stage + histogram by slot
        for (int i = tid; i < cnt; i += 256) {
            int p = ep[e0 + i];
            seS[i] = p;
            atomicAdd(&shist[p & 127], 1);
        }
        __syncthreads();
        // exclusive scan of 128 counters (Hillis-Steele)
        if (tid < TILE) soff[tid + 1] = shist[tid];
        if (tid == 0) soff[0] = 0;
        __syncthreads();
        for (int d = 1; d < TILE; d <<= 1) {
            int v = 0;
            if (tid < TILE && tid >= d) v = soff[tid + 1 - d];
            __syncthreads();
            if (tid < TILE && tid >= d) soff[tid + 1] += v;
            __syncthreads();
        }
        if (tid < TILE) scur[tid] = soff[tid];
        __syncthreads();
        // scatter into slot-sorted order
        for (int i = tid; i < cnt; i += 256) {
            int p = seS[i];
            seD[atomicAdd(&scur[p & 127], 1)] = p;
        }
        __syncthreads();

        // segmented register accumulation: thread = (slot, half); NO per-edge atomics
        int slot = tid & 127, half = tid >> 7;
        float acc[32];
#pragma unroll
        for (int j = 0; j < 32; j++) acc[j] = 0.f;
        int sb = soff[slot], se = soff[slot + 1];
        for (int e = sb; e < se; e++) {
            int src = seD[e] >> 8;
            const u16* xr = &xb[(size_t)src * DD + half * 32];
            uint4 v0 = *(const uint4*)(xr);
            uint4 v1 = *(const uint4*)(xr + 8);
            uint4 v2 = *(const uint4*)(xr + 16);
            uint4 v3 = *(const uint4*)(xr + 24);
#pragma unroll
            for (int q = 0; q < 4; q++) {
                uint4 v = (q == 0) ? v0 : (q == 1) ? v1 : (q == 2) ? v2 : v3;
                acc[q * 8 + 0] += b2f_lo(v.x);
                acc[q * 8 + 1] += b2f_hi(v.x);
                acc[q * 8 + 2] += b2f_lo(v.y);
                acc[q * 8 + 3] += b2f_hi(v.y);
                acc[q * 8 + 4] += b2f_lo(v.z);
                acc[q * 8 + 5] += b2f_hi(v.z);
                acc[q * 8 + 6] += b2f_lo(v.w);
                acc[q * 8 + 7] += b2f_hi(v.w);
            }
        }
        float* hcol = &hs[(size_t)(half * 32) * HSTR + slot];
#pragma unroll
        for (int j = 0; j < 32; j++) hcol[j * HSTR] = acc[j];   // plain ds_write, 2-way = free
        __syncthreads();
        // overflow fallback (bucket > CAP): effectively never runs
        for (int e = e0 + CAP + (tid >> 1); e < e1; e += 128) {
            int p = ep[e];
            int hh = tid & 1;
            int sl = p & 127;
            const u16* xr = &xb[(size_t)(p >> 8) * DD + hh * 32];
            uint4 v0 = *(const uint4*)(xr);
            uint4 v1 = *(const uint4*)(xr + 8);
            uint4 v2 = *(const uint4*)(xr + 16);
            uint4 v3 = *(const uint4*)(xr + 24);
            float* bp = &hs[(size_t)(hh * 32) * HSTR + sl];
#pragma unroll
            for (int q = 0; q < 4; q++) {
                uint4 v = (q == 0) ? v0 : (q == 1) ? v1 : (q == 2) ? v2 : v3;
                atomicAdd(bp + (q * 8 + 0) * HSTR, b2f_lo(v.x));
                atomicAdd(bp + (q * 8 + 1) * HSTR, b2f_hi(v.x));
                atomicAdd(bp + (q * 8 + 2) * HSTR, b2f_lo(v.y));
                atomicAdd(bp + (q * 8 + 3) * HSTR, b2f_hi(v.y));
                atomicAdd(bp + (q * 8 + 4) * HSTR, b2f_lo(v.z));
                atomicAdd(bp + (q * 8 + 5) * HSTR, b2f_hi(v.z));
                atomicAdd(bp + (q * 8 + 6) * HSTR, b2f_lo(v.w));
                atomicAdd(bp + (q * 8 + 7) * HSTR, b2f_hi(v.w));
            }
        }
    } else {
        // root path: stage this x tile transposed into col-major hs
        for (int c = tid; c < TILE * 8; c += 256) {
            int row = c >> 3, c0 = (c & 7) * 8;
            int n = n0 + row;
            uint4 vv = make_uint4(0, 0, 0, 0);
            if (n < NN) vv = *(const uint4*)&xb[(size_t)n * DD + c0];
            hs[(c0 + 0) * HSTR + row] = b2f_lo(vv.x);
            hs[(c0 + 1) * HSTR + row] = b2f_hi(vv.x);
            hs[(c0 + 2) * HSTR + row] = b2f_lo(vv.y);
            hs[(c0 + 3) * HSTR + row] = b2f_hi(vv.y);
            hs[(c0 + 4) * HSTR + row] = b2f_lo(vv.z);
            hs[(c0 + 5) * HSTR + row] = b2f_hi(vv.z);
            hs[(c0 + 6) * HSTR + row] = b2f_lo(vv.w);
            hs[(c0 + 7) * HSTR + row] = b2f_hi(vv.w);
        }
    }
    __syncthreads();

    int tn = tid >> 3;
    int d0 = (tid & 7) * 8;
    int wq = (tid & 7) * 4;

    float facc[4][8];
#pragma unroll
    for (int j = 0; j < 4; j++)
#pragma unroll
        for (int m2 = 0; m2 < 8; m2++) facc[j][m2] = 0.f;

#pragma unroll 4
    for (int kk = 0; kk < DD; kk += 4) {
        float hreg[4][4];
#pragma unroll
        for (int c = 0; c < 4; c++)
#pragma unroll
            for (int j = 0; j < 4; j++)
                hreg[j][c] = hs[(kk + c) * HSTR + tn + 32 * j];   // broadcast b32, conflict-free
#pragma unroll
        for (int c = 0; c < 4; c++) {
            uint4 wp = *(const uint4*)&Wsb[(kk + c) * 32 + wq];
            float w8[8] = {b2f_lo(wp.x), b2f_hi(wp.x), b2f_lo(wp.y), b2f_hi(wp.y),
                           b2f_lo(wp.z), b2f_hi(wp.z), b2f_lo(wp.w), b2f_hi(wp.w)};
#pragma unroll
            for (int j = 0; j < 4; j++)
#pragma unroll
                for (int m2 = 0; m2 < 8; m2++)
                    facc[j][m2] = fmaf(hreg[j][c], w8[m2], facc[j][m2]);
        }
    }

    const float* bvec = root ? rb1l : (b1l + r * DD);
    float bv[8];
#pragma unroll
    for (int m2 = 0; m2 < 8; m2++) bv[m2] = bvec[d0 + m2];

    u16* zout = zb + (size_t)r * NN * DD;
    float s1[8], s2[8];
#pragma unroll
    for (int m2 = 0; m2 < 8; m2++) { s1[m2] = 0.f; s2[m2] = 0.f; }

#pragma unroll
    for (int j = 0; j < 4; j++) {
        int n = n0 + tn + 32 * j;
        if (n < NN) {
            float vv[8];
#pragma unroll
            for (int m2 = 0; m2 < 8; m2++) {
                float v = facc[j][m2] + bv[m2];
                vv[m2] = v;
                s1[m2] += v;
                s2[m2] += v * v;
            }
            uint4 o;
            o.x = pk(vv[0], vv[1]); o.y = pk(vv[2], vv[3]);
            o.z = pk(vv[4], vv[5]); o.w = pk(vv[6], vv[7]);
            *(uint4*)&zout[(size_t)n * DD + d0] = o;
        }
    }

    if (tid < 128) red[tid] = 0.f;
    __syncthreads();
#pragma unroll
    for (int m2 = 0; m2 < 8; m2++) {
        float a = s1[m2], bq = s2[m2];
        a += __shfl_xor(a, 8);  bq += __shfl_xor(bq, 8);
        a += __shfl_xor(a, 16); bq += __shfl_xor(bq, 16);
        a += __shfl_xor(a, 32); bq += __shfl_xor(bq, 32);
        if ((tid & 63) < 8) {
            atomicAdd(&red[d0 + m2], a);
            atomicAdd(&red[64 + d0 + m2], bq);
        }
    }
    __syncthreads();
    if (tid < 64) {
        atomicAdd(&stats[r * DD + tid], red[tid]);
        atomicAdd(&stats[576 + r * DD + tid], red[64 + tid]);
    }
}

// ---------------- finalize: BN affine + fused const bias ----------------

__global__ void finalize_kernel(const float* __restrict__ stats,
                                const float* __restrict__ g1l, const float* __restrict__ be1l,
                                const float* __restrict__ rg1l, const float* __restrict__ rbe1l,
                                const float* __restrict__ b2l, const float* __restrict__ rb2l,
                                const float* __restrict__ biasl,
                                float* __restrict__ affine, float* __restrict__ constd) {
    int t = threadIdx.x;
    if (t < 576) {
        int r = t >> 6, d = t & 63;
        float mean = stats[t] * (1.f / NN);
        float var = fmaxf(stats[576 + t] * (1.f / NN) - mean * mean, 0.f);
        float g  = (r < NR) ? g1l[r * DD + d]  : rg1l[d];
        float be = (r < NR) ? be1l[r * DD + d] : rbe1l[d];
        float sc = g * rsqrtf(var + EPSB);
        affine[t] = sc;
        affine[576 + t] = be - mean * sc;
        if (r == 0) {
            float cd = rb2l[d] + biasl[d];
#pragma unroll
            for (int rr = 0; rr < NR; rr++) cd += b2l[rr * DD + d];
            constd[d] = cd;
        }
    }
}

// ---------------- pass2: out = sum_r relu(bn(z_r)) @ W2_r + const ----------------

__launch_bounds__(256, 3)
__global__ void pass2_kernel(const u16* __restrict__ zb,
                             const float* __restrict__ W2l, const float* __restrict__ rW2l,
                             const float* __restrict__ affine, const float* __restrict__ constd,
                             float* __restrict__ outf, u16* __restrict__ outb,
                             int emit_bf16_relu) {
    __shared__ __align__(16) float zs[TILE][68];
    __shared__ __align__(16) float W2s[DD][DD];
    int n0 = blockIdx.x * TILE;
    int tid = threadIdx.x;
    int tn = tid >> 3;
    int d0 = (tid & 7) * 8;
    int srow = tid >> 3;
    int sc0 = (tid & 7) * 8;

    float acc[4][8];
#pragma unroll
    for (int j = 0; j < 4; j++)
#pragma unroll
        for (int m = 0; m < 8; m++) acc[j][m] = 0.f;

    uint4 pre[4];
    {
        const u16* zp = zb;
#pragma unroll
        for (int q = 0; q < 4; q++) {
            int n = n0 + srow + 32 * q;
            pre[q] = (n < NN) ? *(const uint4*)&zp[(size_t)n * DD + sc0]
                              : make_uint4(0, 0, 0, 0);
        }
    }

    for (int r = 0; r < 9; r++) {
        float4 aLo = *(const float4*)&affine[r * DD + sc0];
        float4 aHi = *(const float4*)&affine[r * DD + sc0 + 4];
        float4 cLo = *(const float4*)&affine[576 + r * DD + sc0];
        float4 cHi = *(const float4*)&affine[576 + r * DD + sc0 + 4];
        __syncthreads();
#pragma unroll
        for (int q = 0; q < 4; q++) {
            uint4 vv = pre[q];
            float4 A = make_float4(b2f_lo(vv.x), b2f_hi(vv.x), b2f_lo(vv.y), b2f_hi(vv.y));
            float4 B = make_float4(b2f_lo(vv.z), b2f_hi(vv.z), b2f_lo(vv.w), b2f_hi(vv.w));
            A.x = fmaxf(fmaf(A.x, aLo.x, cLo.x), 0.f);
            A.y = fmaxf(fmaf(A.y, aLo.y, cLo.y), 0.f);
            A.z = fmaxf(fmaf(A.z, aLo.z, cLo.z), 0.f);
            A.w = fmaxf(fmaf(A.w, aLo.w, cLo.w), 0.f);
            B.x = fmaxf(fmaf(B.x, aHi.x, cHi.x), 0.f);
            B.y = fmaxf(fmaf(B.y, aHi.y, cHi.y), 0.f);
            B.z = fmaxf(fmaf(B.z, aHi.z, cHi.z), 0.f);
            B.w = fmaxf(fmaf(B.w, aHi.w, cHi.w), 0.f);
            *(float4*)&zs[srow + 32 * q][sc0]     = A;
            *(float4*)&zs[srow + 32 * q][sc0 + 4] = B;
        }
        const float* W = (r < NR) ? (W2l + (size_t)r * DD * DD) : rW2l;
        for (int idx = tid; idx < DD * DD; idx += 256)
            ((float*)W2s)[idx] = W[idx];
        __syncthreads();
        if (r + 1 < 9) {
            const u16* zp = zb + (size_t)(r + 1) * NN * DD;
#pragma unroll
            for (int q = 0; q < 4; q++) {
                int n = n0 + srow + 32 * q;
                pre[q] = (n < NN) ? *(const uint4*)&zp[(size_t)n * DD + sc0]
                                  : make_uint4(0, 0, 0, 0);
            }
        }

#pragma unroll 4
        for (int kk = 0; kk < DD; kk += 4) {
            float hreg[4][4];
#pragma unroll
            for (int j = 0; j < 4; j++) {
                float4 t4 = *(const float4*)&zs[tn + 32 * j][kk];
                hreg[j][0] = t4.x; hreg[j][1] = t4.y; hreg[j][2] = t4.z; hreg[j][3] = t4.w;
            }
#pragma unroll
            for (int c = 0; c < 4; c++) {
                float4 wa = *(const float4*)&W2s[kk + c][d0];
                float4 wb = *(const float4*)&W2s[kk + c][d0 + 4];
                float w8[8] = {wa.x, wa.y, wa.z, wa.w, wb.x, wb.y, wb.z, wb.w};
#pragma unroll
                for (int j = 0; j < 4; j++)
#pragma unroll
                    for (int m = 0; m < 8; m++)
                        acc[j][m] = fmaf(hreg[j][c], w8[m], acc[j][m]);
            }
        }
    }

    float cd[8];
#pragma unroll
    for (int m = 0; m < 8; m++) cd[m] = constd[d0 + m];

#pragma unroll
    for (int j = 0; j < 4; j++) {
        int n = n0 + tn + 32 * j;
        if (n < NN) {
            float vv[8];
#pragma unroll
            for (int m = 0; m < 8; m++) vv[m] = acc[j][m] + cd[m];
            if (emit_bf16_relu) {
#pragma unroll
                for (int m = 0; m < 8; m++) vv[m] = fmaxf(vv[m], 0.f);
                uint4 o;
                o.x = pk(vv[0], vv[1]); o.y = pk(vv[2], vv[3]);
                o.z = pk(vv[4], vv[5]); o.w = pk(vv[6], vv[7]);
                *(uint4*)&outb[(size_t)n * DD + d0] = o;
            } else {
                *(float4*)&outf[(size_t)n * DD + d0]     = make_float4(vv[0], vv[1], vv[2], vv[3]);
                *(float4*)&outf[(size_t)n * DD + d0 + 4] = make_float4(vv[4], vv[5], vv[6], vv[7]);
            }
        }
    }
}

// ---------------- host ----------------

extern "C" void kernel_launch(void* const* d_in, const int* in_sizes, int n_in,
                              void* d_out, int out_size, void* d_ws, size_t ws_size,
                              hipStream_t stream) {
    (void)in_sizes; (void)n_in; (void)out_size;

    const float* x0   = (const float*)d_in[0];
    const int*   ei   = (const int*)d_in[1];
    const int*   et   = (const int*)d_in[2];
    const float* W1   = (const float*)d_in[3];
    const float* b1   = (const float*)d_in[4];
    const float* g1   = (const float*)d_in[5];
    const float* be1  = (const float*)d_in[6];
    const float* W2   = (const float*)d_in[7];
    const float* b2   = (const float*)d_in[8];
    const float* rW1  = (const float*)d_in[9];
    const float* rb1  = (const float*)d_in[10];
    const float* rg1  = (const float*)d_in[11];
    const float* rbe1 = (const float*)d_in[12];
    const float* rW2  = (const float*)d_in[13];
    const float* rb2  = (const float*)d_in[14];
    const float* bias = (const float*)d_in[15];
    float* out = (float*)d_out;

    char* ws = (char*)d_ws;
    size_t zelems = (size_t)9 * NN * DD;
    u16* zb = (u16*)ws;                               // 9*NN*DD bf16
    u16* xb = zb + zelems;                            // NN*DD bf16 (layer input; pass2 rewrites for layer 1)
    float* stats  = (float*)(xb + (size_t)NN * DD);   // 1152
    float* affine = stats + 1152;                     // 1152
    float* constd = affine + 1152;                    // 64
    int* cnt    = (int*)(constd + 64);                // NBUCKETS
    int* cursor = cnt + NBUCKETS;                     // NBUCKETS
    int* off    = cursor + NBUCKETS;                  // NBUCKETS+1
    int* ep     = off + NBUCKETS + 1;                 // NE

    size_t need = (zelems + (size_t)NN * DD) * 2
                + (1152 + 1152 + 64) * 4
                + ((size_t)3 * NBUCKETS + 1 + NE) * 4;
    if (ws_size < need) return;

    cvt_kernel<<<(NN * DD / 8 + 255) / 256, 256, 0, stream>>>(x0, xb);
    hipMemsetAsync(cnt, 0, sizeof(int) * 2 * NBUCKETS, stream);
    count_kernel<<<(NE + 255) / 256, 256, 0, stream>>>(ei + NE, et, cnt);
    scan_kernel<<<1, 1024, 0, stream>>>(cnt, off, NBUCKETS);
    fill_kernel<<<(NE + 255) / 256, 256, 0, stream>>>(ei, ei + NE, et, off, cursor, ep);

    for (int i = 0; i < 2; i++) {
        hipMemsetAsync(stats, 0, sizeof(float) * 1152, stream);
        gemm1_kernel<<<dim3(NTILES, 9), 256, 0, stream>>>(
            xb, ep, off,
            W1 + (size_t)i * NR * DD * DD, b1 + (size_t)i * NR * DD,
            rW1 + (size_t)i * DD * DD, rb1 + (size_t)i * DD,
            zb, stats);
        finalize_kernel<<<1, 576, 0, stream>>>(
            stats,
            g1 + (size_t)i * NR * DD, be1 + (size_t)i * NR * DD,
            rg1 + (size_t)i * DD, rbe1 + (size_t)i * DD,
            b2 + (size_t)i * NR * DD, rb2 + (size_t)i * DD, bias + (size_t)i * DD,
            affine, constd);
        pass2_kernel<<<NTILES, 256, 0, stream>>>(
            zb, W2 + (size_t)i * NR * DD * DD, rW2 + (size_t)i * DD * DD,
            affine, constd, out, xb, (i == 0) ? 1 : 0);
    }
}

// Round 10
// 579.026 us; speedup vs baseline: 4.0306x; 1.3173x over previous
//
#include <hip/hip_runtime.h>

#define NN 100000
#define NE 1250000
#define NR 8
#define DD 64
#define TILE 128
#define NTILES 782                 // ceil(100000/128)
#define NBUCKETS (NR * NTILES)     // 6256 dst-buckets (rel, dst-tile)
#define CAP 512                    // sort-chunk size (Poisson(200): 1 chunk typical)
#define HROW 72                    // bf16 LDS row stride (144B = 36 dw: conflict-free b128 frags)
#define EPSB 1e-5f

typedef unsigned short u16;
typedef unsigned int u32;
typedef __attribute__((ext_vector_type(8))) short short8;   // 8 bf16 = 4 VGPR (MFMA A/B frag)
typedef __attribute__((ext_vector_type(4))) float f32x4;    // MFMA C/D frag

static __device__ __forceinline__ float b2f_lo(u32 v) { return __uint_as_float(v << 16); }
static __device__ __forceinline__ float b2f_hi(u32 v) { return __uint_as_float(v & 0xffff0000u); }
static __device__ __forceinline__ u16 f2b(float f) {
    u32 u = __float_as_uint(f);
    u += 0x7fffu + ((u >> 16) & 1u);   // round-to-nearest-even
    return (u16)(u >> 16);
}
static __device__ __forceinline__ u32 pk(float a, float b) {
    return (u32)f2b(a) | ((u32)f2b(b) << 16);
}

// ---------------- fp32 -> bf16 copy of x ----------------

__global__ void cvt_kernel(const float* __restrict__ in, u16* __restrict__ outb) {
    int i = blockIdx.x * 256 + threadIdx.x;
    if (i < NN * DD / 8) {
        float4 a = *(const float4*)&in[i * 8];
        float4 b = *(const float4*)&in[i * 8 + 4];
        uint4 o;
        o.x = pk(a.x, a.y); o.y = pk(a.z, a.w);
        o.z = pk(b.x, b.y); o.w = pk(b.z, b.w);
        *(uint4*)&outb[i * 8] = o;
    }
}

// ---------------- dst-CSR build (once per call) ----------------

__global__ void count_kernel(const int* __restrict__ dst,
                             const int* __restrict__ et,
                             int* __restrict__ cnt) {
    int i = blockIdx.x * 256 + threadIdx.x;
    if (i < NE) atomicAdd(&cnt[et[i] * NTILES + (dst[i] >> 7)], 1);
}

__global__ void scan_kernel(const int* __restrict__ cnt, int* __restrict__ off, int n) {
    __shared__ int ts[1024];
    int t = threadIdx.x;
    int v[8];
    int s = 0;
#pragma unroll
    for (int j = 0; j < 8; j++) {
        int idx = t * 8 + j;
        int c = (idx < n) ? cnt[idx] : 0;
        v[j] = s;
        s += c;
    }
    ts[t] = s;
    __syncthreads();
    for (int d = 1; d < 1024; d <<= 1) {
        int add = (t >= d) ? ts[t - d] : 0;
        __syncthreads();
        ts[t] += add;
        __syncthreads();
    }
    int base = (t > 0) ? ts[t - 1] : 0;
#pragma unroll
    for (int j = 0; j < 8; j++) {
        int idx = t * 8 + j;
        if (idx < n) off[idx] = base + v[j];
    }
    if (t == 1023) off[n] = ts[1023];
}

__global__ void fill_kernel(const int* __restrict__ src, const int* __restrict__ dst,
                            const int* __restrict__ et, const int* __restrict__ off,
                            int* __restrict__ cursor, int* __restrict__ ep) {
    int i = blockIdx.x * 256 + threadIdx.x;
    if (i < NE) {
        int d = dst[i];
        int b = et[i] * NTILES + (d >> 7);
        int pos = off[b] + atomicAdd(&cursor[b], 1);
        ep[pos] = (src[i] << 8) | (d & 127);
    }
}

// ---------------- gemm1: sort+register gather -> bf16 LDS -> MFMA z=h@W1+b1, BN stats ----------------

__launch_bounds__(256, 4)
__global__ void gemm1_kernel(const u16* __restrict__ xb,
                             const int* __restrict__ ep, const int* __restrict__ off,
                             const float* __restrict__ W1l, const float* __restrict__ b1l,
                             const float* __restrict__ rW1l, const float* __restrict__ rb1l,
                             u16* __restrict__ zb, float* __restrict__ stats) {
    __shared__ u16 hsb[TILE * HROW];      // 18KB bf16 h-tile (then reused for z)
    __shared__ u16 wtb[DD * HROW];        // 9KB  Wt[d][k] bf16
    __shared__ int seS[CAP], seD[CAP];
    __shared__ int shist[TILE], scur[TILE], soff[TILE + 1];
    __shared__ float red[2 * DD];
    int r = blockIdx.y;
    bool root = (r == NR);
    int n0 = blockIdx.x * TILE;
    int tid = threadIdx.x;

    // stage W transposed as bf16: wtb[d][k], u32-pair writes along k
    const float* W = root ? rW1l : (W1l + (size_t)r * DD * DD);
    for (int i = tid; i < DD * 32; i += 256) {
        int d = i >> 5, kp = i & 31;
        ((u32*)wtb)[d * (HROW / 2) + kp] = pk(W[(2 * kp) * DD + d], W[(2 * kp + 1) * DD + d]);
    }
    if (tid < 128) red[tid] = 0.f;

    if (!root) {
        int b = r * NTILES + blockIdx.x;
        int e0 = off[b], e1 = off[b + 1];
        int m = e1 - e0;
        int slot = tid & 127, half = tid >> 7;
        float acc[32];
#pragma unroll
        for (int j = 0; j < 32; j++) acc[j] = 0.f;

        for (int base = 0; base < m; base += CAP) {
            int cnt = min(m - base, CAP);
            if (tid < TILE) shist[tid] = 0;
            __syncthreads();
            for (int i = tid; i < cnt; i += 256) {
                int p = ep[e0 + base + i];
                seS[i] = p;
                atomicAdd(&shist[p & 127], 1);
            }
            __syncthreads();
            if (tid < TILE) soff[tid + 1] = shist[tid];
            if (tid == 0) soff[0] = 0;
            __syncthreads();
            for (int d = 1; d < TILE; d <<= 1) {
                int v = 0;
                if (tid < TILE && tid >= d) v = soff[tid + 1 - d];
                __syncthreads();
                if (tid < TILE && tid >= d) soff[tid + 1] += v;
                __syncthreads();
            }
            if (tid < TILE) scur[tid] = soff[tid];
            __syncthreads();
            for (int i = tid; i < cnt; i += 256) {
                int p = seS[i];
                seD[atomicAdd(&scur[p & 127], 1)] = p;
            }
            __syncthreads();
            int sb = soff[slot], se = soff[slot + 1];
            for (int e = sb; e < se; e++) {
                int src = seD[e] >> 8;
                const u16* xr = &xb[(size_t)src * DD + half * 32];
                uint4 v0 = *(const uint4*)(xr);
                uint4 v1 = *(const uint4*)(xr + 8);
                uint4 v2 = *(const uint4*)(xr + 16);
                uint4 v3 = *(const uint4*)(xr + 24);
#pragma unroll
                for (int q = 0; q < 4; q++) {
                    uint4 v = (q == 0) ? v0 : (q == 1) ? v1 : (q == 2) ? v2 : v3;
                    acc[q * 8 + 0] += b2f_lo(v.x);
                    acc[q * 8 + 1] += b2f_hi(v.x);
                    acc[q * 8 + 2] += b2f_lo(v.y);
                    acc[q * 8 + 3] += b2f_hi(v.y);
                    acc[q * 8 + 4] += b2f_lo(v.z);
                    acc[q * 8 + 5] += b2f_hi(v.z);
                    acc[q * 8 + 6] += b2f_lo(v.w);
                    acc[q * 8 + 7] += b2f_hi(v.w);
                }
            }
            __syncthreads();   // protect seD before next chunk restage
        }
        // pack h to bf16, one conflict-free write burst per thread
        u32 pw[16];
#pragma unroll
        for (int j = 0; j < 16; j++) pw[j] = pk(acc[2 * j], acc[2 * j + 1]);
        u16* hrow = &hsb[slot * HROW + half * 32];
        *(uint4*)(hrow)      = make_uint4(pw[0], pw[1], pw[2], pw[3]);
        *(uint4*)(hrow + 8)  = make_uint4(pw[4], pw[5], pw[6], pw[7]);
        *(uint4*)(hrow + 16) = make_uint4(pw[8], pw[9], pw[10], pw[11]);
        *(uint4*)(hrow + 24) = make_uint4(pw[12], pw[13], pw[14], pw[15]);
    } else {
        for (int idx = tid; idx < TILE * 8; idx += 256) {
            int row = idx >> 3, q = idx & 7;
            int n = n0 + row;
            uint4 v = make_uint4(0, 0, 0, 0);
            if (n < NN) v = *(const uint4*)&xb[(size_t)n * DD + q * 8];
            *(uint4*)&hsb[row * HROW + q * 8] = v;
        }
    }
    __syncthreads();

    // ---- MFMA: wave w owns rows 32w..32w+31, all 64 cols ----
    int wv = tid >> 6;
    int l  = tid & 63;
    int lr = l & 15;    // A row / B col / D col
    int lg = l >> 4;    // k-group / D row-group

    f32x4 dacc[2][4];
#pragma unroll
    for (int rt = 0; rt < 2; rt++)
#pragma unroll
        for (int ct = 0; ct < 4; ct++) dacc[rt][ct] = (f32x4){0.f, 0.f, 0.f, 0.f};

#pragma unroll
    for (int ks = 0; ks < 2; ks++) {
        short8 afr[2];
#pragma unroll
        for (int rt = 0; rt < 2; rt++)
            afr[rt] = *(const short8*)&hsb[(wv * 32 + rt * 16 + lr) * HROW + ks * 32 + lg * 8];
#pragma unroll
        for (int ct = 0; ct < 4; ct++) {
            short8 bfr = *(const short8*)&wtb[(ct * 16 + lr) * HROW + ks * 32 + lg * 8];
            dacc[0][ct] = __builtin_amdgcn_mfma_f32_16x16x32_bf16(afr[0], bfr, dacc[0][ct], 0, 0, 0);
            dacc[1][ct] = __builtin_amdgcn_mfma_f32_16x16x32_bf16(afr[1], bfr, dacc[1][ct], 0, 0, 0);
        }
    }

    // bias + BN stats (per-lane cols 16ct+lr, rows wv*32+rt*16+lg*4+i)
    const float* bvec = root ? rb1l : (b1l + r * DD);
    float bv4[4], s1v[4], s2v[4];
#pragma unroll
    for (int ct = 0; ct < 4; ct++) { bv4[ct] = bvec[16 * ct + lr]; s1v[ct] = 0.f; s2v[ct] = 0.f; }
#pragma unroll
    for (int rt = 0; rt < 2; rt++)
#pragma unroll
        for (int ct = 0; ct < 4; ct++)
#pragma unroll
            for (int i = 0; i < 4; i++) {
                float v = dacc[rt][ct][i] + bv4[ct];
                dacc[rt][ct][i] = v;
                int n = n0 + wv * 32 + rt * 16 + lg * 4 + i;
                if (n < NN) { s1v[ct] += v; s2v[ct] += v * v; }
            }
#pragma unroll
    for (int ct = 0; ct < 4; ct++) {
        float a = s1v[ct], bq = s2v[ct];
        a += __shfl_xor(a, 16); bq += __shfl_xor(bq, 16);
        a += __shfl_xor(a, 32); bq += __shfl_xor(bq, 32);
        if (lg == 0) {
            atomicAdd(&red[16 * ct + lr], a);
            atomicAdd(&red[64 + 16 * ct + lr], bq);
        }
    }
    __syncthreads();   // hsb reads done; red complete

    // scatter z (bf16) into hsb, then coalesced flush
#pragma unroll
    for (int rt = 0; rt < 2; rt++)
#pragma unroll
        for (int ct = 0; ct < 4; ct++)
#pragma unroll
            for (int i = 0; i < 4; i++)
                hsb[(wv * 32 + rt * 16 + lg * 4 + i) * HROW + 16 * ct + lr] = f2b(dacc[rt][ct][i]);
    __syncthreads();

    u16* zout = zb + (size_t)r * NN * DD;
    for (int idx = tid; idx < TILE * 8; idx += 256) {
        int row = idx >> 3, q = idx & 7;
        int n = n0 + row;
        if (n < NN)
            *(uint4*)&zout[(size_t)n * DD + q * 8] = *(const uint4*)&hsb[row * HROW + q * 8];
    }
    if (tid < 64) {
        atomicAdd(&stats[r * DD + tid], red[tid]);
        atomicAdd(&stats[576 + r * DD + tid], red[64 + tid]);
    }
}

// ---------------- finalize: BN affine + fused const bias ----------------

__global__ void finalize_kernel(const float* __restrict__ stats,
                                const float* __restrict__ g1l, const float* __restrict__ be1l,
                                const float* __restrict__ rg1l, const float* __restrict__ rbe1l,
                                const float* __restrict__ b2l, const float* __restrict__ rb2l,
                                const float* __restrict__ biasl,
                                float* __restrict__ affine, float* __restrict__ constd) {
    int t = threadIdx.x;
    if (t < 576) {
        int r = t >> 6, d = t & 63;
        float mean = stats[t] * (1.f / NN);
        float var = fmaxf(stats[576 + t] * (1.f / NN) - mean * mean, 0.f);
        float g  = (r < NR) ? g1l[r * DD + d]  : rg1l[d];
        float be = (r < NR) ? be1l[r * DD + d] : rbe1l[d];
        float sc = g * rsqrtf(var + EPSB);
        affine[t] = sc;
        affine[576 + t] = be - mean * sc;
        if (r == 0) {
            float cd = rb2l[d] + biasl[d];
#pragma unroll
            for (int rr = 0; rr < NR; rr++) cd += b2l[rr * DD + d];
            constd[d] = cd;
        }
    }
}

// ---------------- pass2: MFMA out = sum_r relu(bn(z_r)) @ W2_r + const ----------------

__launch_bounds__(256, 4)
__global__ void pass2_kernel(const u16* __restrict__ zb,
                             const float* __restrict__ W2l, const float* __restrict__ rW2l,
                             const float* __restrict__ affine, const float* __restrict__ constd,
                             float* __restrict__ outf, u16* __restrict__ outb,
                             int emit_bf16_relu) {
    __shared__ u16 zsb[TILE * HROW];      // 18KB bf16 activated z-tile (reused for output)
    __shared__ u16 wtb[DD * HROW];        // 9KB Wt[d][k]
    int n0 = blockIdx.x * TILE;
    int tid = threadIdx.x;
    int srow = tid >> 3;          // staging row base (0..31), rows srow+32q
    int sc0 = (tid & 7) * 8;      // staging col base

    int wv = tid >> 6;
    int l  = tid & 63;
    int lr = l & 15;
    int lg = l >> 4;

    f32x4 dacc[2][4];
#pragma unroll
    for (int rt = 0; rt < 2; rt++)
#pragma unroll
        for (int ct = 0; ct < 4; ct++) dacc[rt][ct] = (f32x4){0.f, 0.f, 0.f, 0.f};

    uint4 pre[4];
    {
        const u16* zp = zb;
#pragma unroll
        for (int q = 0; q < 4; q++) {
            int n = n0 + srow + 32 * q;
            pre[q] = (n < NN) ? *(const uint4*)&zp[(size_t)n * DD + sc0]
                              : make_uint4(0, 0, 0, 0);
        }
    }

    for (int r = 0; r < 9; r++) {
        float4 aLo = *(const float4*)&affine[r * DD + sc0];
        float4 aHi = *(const float4*)&affine[r * DD + sc0 + 4];
        float4 cLo = *(const float4*)&affine[576 + r * DD + sc0];
        float4 cHi = *(const float4*)&affine[576 + r * DD + sc0 + 4];
        __syncthreads();   // previous iteration's MFMA frag-reads done
        // write activated tile (bf16) into zsb
#pragma unroll
        for (int q = 0; q < 4; q++) {
            uint4 vv = pre[q];
            float a0 = fmaxf(fmaf(b2f_lo(vv.x), aLo.x, cLo.x), 0.f);
            float a1 = fmaxf(fmaf(b2f_hi(vv.x), aLo.y, cLo.y), 0.f);
            float a2 = fmaxf(fmaf(b2f_lo(vv.y), aLo.z, cLo.z), 0.f);
            float a3 = fmaxf(fmaf(b2f_hi(vv.y), aLo.w, cLo.w), 0.f);
            float a4 = fmaxf(fmaf(b2f_lo(vv.z), aHi.x, cHi.x), 0.f);
            float a5 = fmaxf(fmaf(b2f_hi(vv.z), aHi.y, cHi.y), 0.f);
            float a6 = fmaxf(fmaf(b2f_lo(vv.w), aHi.z, cHi.z), 0.f);
            float a7 = fmaxf(fmaf(b2f_hi(vv.w), aHi.w, cHi.w), 0.f);
            uint4 o = make_uint4(pk(a0, a1), pk(a2, a3), pk(a4, a5), pk(a6, a7));
            *(uint4*)&zsb[(srow + 32 * q) * HROW + sc0] = o;
        }
        // stage W2^T bf16
        const float* W = (r < NR) ? (W2l + (size_t)r * DD * DD) : rW2l;
        for (int i = tid; i < DD * 32; i += 256) {
            int d = i >> 5, kp = i & 31;
            ((u32*)wtb)[d * (HROW / 2) + kp] = pk(W[(2 * kp) * DD + d], W[(2 * kp + 1) * DD + d]);
        }
        __syncthreads();
        // prefetch next relation's z
        if (r + 1 < 9) {
            const u16* zp = zb + (size_t)(r + 1) * NN * DD;
#pragma unroll
            for (int q = 0; q < 4; q++) {
                int n = n0 + srow + 32 * q;
                pre[q] = (n < NN) ? *(const uint4*)&zp[(size_t)n * DD + sc0]
                                  : make_uint4(0, 0, 0, 0);
            }
        }
        // MFMA
#pragma unroll
        for (int ks = 0; ks < 2; ks++) {
            short8 afr[2];
#pragma unroll
            for (int rt = 0; rt < 2; rt++)
                afr[rt] = *(const short8*)&zsb[(wv * 32 + rt * 16 + lr) * HROW + ks * 32 + lg * 8];
#pragma unroll
            for (int ct = 0; ct < 4; ct++) {
                short8 bfr = *(const short8*)&wtb[(ct * 16 + lr) * HROW + ks * 32 + lg * 8];
                dacc[0][ct] = __builtin_amdgcn_mfma_f32_16x16x32_bf16(afr[0], bfr, dacc[0][ct], 0, 0, 0);
                dacc[1][ct] = __builtin_amdgcn_mfma_f32_16x16x32_bf16(afr[1], bfr, dacc[1][ct], 0, 0, 0);
            }
        }
    }

    float cd4[4];
#pragma unroll
    for (int ct = 0; ct < 4; ct++) cd4[ct] = constd[16 * ct + lr];

    if (emit_bf16_relu) {
        __syncthreads();
#pragma unroll
        for (int rt = 0; rt < 2; rt++)
#pragma unroll
            for (int ct = 0; ct < 4; ct++)
#pragma unroll
                for (int i = 0; i < 4; i++) {
                    float v = fmaxf(dacc[rt][ct][i] + cd4[ct], 0.f);
                    zsb[(wv * 32 + rt * 16 + lg * 4 + i) * HROW + 16 * ct + lr] = f2b(v);
                }
        __syncthreads();
        for (int idx = tid; idx < TILE * 8; idx += 256) {
            int row = idx >> 3, q = idx & 7;
            int n = n0 + row;
            if (n < NN)
                *(uint4*)&outb[(size_t)n * DD + q * 8] = *(const uint4*)&zsb[row * HROW + q * 8];
        }
    } else {
        float* zf = (float*)zsb;   // 128 x 34 f32 fits in 18KB
#pragma unroll
        for (int h = 0; h < 2; h++) {
            __syncthreads();
#pragma unroll
            for (int rt = 0; rt < 2; rt++)
#pragma unroll
                for (int cc = 0; cc < 2; cc++) {
                    int ct = 2 * h + cc;
#pragma unroll
                    for (int i = 0; i < 4; i++)
                        zf[(wv * 32 + rt * 16 + lg * 4 + i) * 34 + 16 * cc + lr] =
                            dacc[rt][ct][i] + cd4[ct];
                }
            __syncthreads();
            for (int idx = tid; idx < TILE * 8; idx += 256) {
                int row = idx >> 3, q = idx & 7;
                int n = n0 + row;
                if (n < NN)
                    *(float4*)&outf[(size_t)n * DD + 32 * h + q * 4] =
                        *(const float4*)&zf[row * 34 + q * 4];
            }
        }
    }
}

// ---------------- host ----------------

extern "C" void kernel_launch(void* const* d_in, const int* in_sizes, int n_in,
                              void* d_out, int out_size, void* d_ws, size_t ws_size,
                              hipStream_t stream) {
    (void)in_sizes; (void)n_in; (void)out_size;

    const float* x0   = (const float*)d_in[0];
    const int*   ei   = (const int*)d_in[1];
    const int*   et   = (const int*)d_in[2];
    const float* W1   = (const float*)d_in[3];
    const float* b1   = (const float*)d_in[4];
    const float* g1   = (const float*)d_in[5];
    const float* be1  = (const float*)d_in[6];
    const float* W2   = (const float*)d_in[7];
    const float* b2   = (const float*)d_in[8];
    const float* rW1  = (const float*)d_in[9];
    const float* rb1  = (const float*)d_in[10];
    const float* rg1  = (const float*)d_in[11];
    const float* rbe1 = (const float*)d_in[12];
    const float* rW2  = (const float*)d_in[13];
    const float* rb2  = (const float*)d_in[14];
    const float* bias = (const float*)d_in[15];
    float* out = (float*)d_out;

    char* ws = (char*)d_ws;
    size_t zelems = (size_t)9 * NN * DD;
    u16* zb = (u16*)ws;                               // 9*NN*DD bf16
    u16* xb = zb + zelems;                            // NN*DD bf16 (layer input; pass2 rewrites for layer 1)
    float* stats  = (float*)(xb + (size_t)NN * DD);   // 1152
    float* affine = stats + 1152;                     // 1152
    float* constd = affine + 1152;                    // 64
    int* cnt    = (int*)(constd + 64);                // NBUCKETS
    int* cursor = cnt + NBUCKETS;                     // NBUCKETS
    int* off    = cursor + NBUCKETS;                  // NBUCKETS+1
    int* ep     = off + NBUCKETS + 1;                 // NE

    size_t need = (zelems + (size_t)NN * DD) * 2
                + (1152 + 1152 + 64) * 4
                + ((size_t)3 * NBUCKETS + 1 + NE) * 4;
    if (ws_size < need) return;

    cvt_kernel<<<(NN * DD / 8 + 255) / 256, 256, 0, stream>>>(x0, xb);
    hipMemsetAsync(cnt, 0, sizeof(int) * 2 * NBUCKETS, stream);
    count_kernel<<<(NE + 255) / 256, 256, 0, stream>>>(ei + NE, et, cnt);
    scan_kernel<<<1, 1024, 0, stream>>>(cnt, off, NBUCKETS);
    fill_kernel<<<(NE + 255) / 256, 256, 0, stream>>>(ei, ei + NE, et, off, cursor, ep);

    for (int i = 0; i < 2; i++) {
        hipMemsetAsync(stats, 0, sizeof(float) * 1152, stream);
        gemm1_kernel<<<dim3(NTILES, 9), 256, 0, stream>>>(
            xb, ep, off,
            W1 + (size_t)i * NR * DD * DD, b1 + (size_t)i * NR * DD,
            rW1 + (size_t)i * DD * DD, rb1 + (size_t)i * DD,
            zb, stats);
        finalize_kernel<<<1, 576, 0, stream>>>(
            stats,
            g1 + (size_t)i * NR * DD, be1 + (size_t)i * NR * DD,
            rg1 + (size_t)i * DD, rbe1 + (size_t)i * DD,
            b2 + (size_t)i * NR * DD, rb2 + (size_t)i * DD, bias + (size_t)i * DD,
            affine, constd);
        pass2_kernel<<<NTILES, 256, 0, stream>>>(
            zb, W2 + (size_t)i * NR * DD * DD, rW2 + (size_t)i * DD * DD,
            affine, constd, out, xb, (i == 0) ? 1 : 0);
    }
}

// Round 11
// 493.736 us; speedup vs baseline: 4.7268x; 1.1727x over previous
//
#include <hip/hip_runtime.h>

#define NN 100000
#define NE 1250000
#define NR 8
#define DD 64
#define TILE 128
#define NTILES 782                 // ceil(100000/128)
#define NBUCKETS (NR * NTILES)     // 6256 dst-buckets (rel, dst-tile)
#define CAP 512                    // sort-chunk size (Poisson(200): 1 chunk typical)
#define HROW 72                    // bf16 LDS row stride (144B: conflict-free b128 frags)
#define EPSB 1e-5f

typedef unsigned short u16;
typedef unsigned int u32;
typedef __attribute__((ext_vector_type(8))) short short8;   // 8 bf16 = 4 VGPR (MFMA A/B frag)
typedef __attribute__((ext_vector_type(4))) float f32x4;    // MFMA C/D frag

static __device__ __forceinline__ float b2f_lo(u32 v) { return __uint_as_float(v << 16); }
static __device__ __forceinline__ float b2f_hi(u32 v) { return __uint_as_float(v & 0xffff0000u); }
static __device__ __forceinline__ u16 f2b(float f) {
    u32 u = __float_as_uint(f);
    u += 0x7fffu + ((u >> 16) & 1u);   // round-to-nearest-even
    return (u16)(u >> 16);
}
static __device__ __forceinline__ u32 pk(float a, float b) {
    return (u32)f2b(a) | ((u32)f2b(b) << 16);
}
static __device__ __forceinline__ void acc8(float* acc, uint4 v0, uint4 v1, uint4 v2, uint4 v3) {
#pragma unroll
    for (int q = 0; q < 4; q++) {
        uint4 v = (q == 0) ? v0 : (q == 1) ? v1 : (q == 2) ? v2 : v3;
        acc[q * 8 + 0] += b2f_lo(v.x);
        acc[q * 8 + 1] += b2f_hi(v.x);
        acc[q * 8 + 2] += b2f_lo(v.y);
        acc[q * 8 + 3] += b2f_hi(v.y);
        acc[q * 8 + 4] += b2f_lo(v.z);
        acc[q * 8 + 5] += b2f_hi(v.z);
        acc[q * 8 + 6] += b2f_lo(v.w);
        acc[q * 8 + 7] += b2f_hi(v.w);
    }
}

// ---------------- fp32 -> bf16 copy of x ----------------

__global__ void cvt_kernel(const float* __restrict__ in, u16* __restrict__ outb) {
    int i = blockIdx.x * 256 + threadIdx.x;
    if (i < NN * DD / 8) {
        float4 a = *(const float4*)&in[i * 8];
        float4 b = *(const float4*)&in[i * 8 + 4];
        uint4 o;
        o.x = pk(a.x, a.y); o.y = pk(a.z, a.w);
        o.z = pk(b.x, b.y); o.w = pk(b.z, b.w);
        *(uint4*)&outb[i * 8] = o;
    }
}

// ---------------- weight pre-transpose: Wt[d][k] bf16, all 36 matrices ----------------

__global__ void wt_kernel(const float* __restrict__ W1, const float* __restrict__ rW1,
                          const float* __restrict__ W2, const float* __restrict__ rW2,
                          u16* __restrict__ wt1g, u16* __restrict__ wt2g) {
    int m = blockIdx.x;                  // 0..35
    int i = m / 18, rest = m % 18;
    int set = rest / 9, r = rest % 9;
    const float* W = (set == 0)
        ? ((r < NR) ? (W1 + ((size_t)i * NR + r) * DD * DD) : (rW1 + (size_t)i * DD * DD))
        : ((r < NR) ? (W2 + ((size_t)i * NR + r) * DD * DD) : (rW2 + (size_t)i * DD * DD));
    u32* dst = (u32*)((set == 0 ? wt1g : wt2g) + ((size_t)i * 9 + r) * DD * DD);
    for (int j = threadIdx.x; j < DD * 32; j += 256) {
        int d = j >> 5, kp = j & 31;
        dst[j] = pk(W[(2 * kp) * DD + d], W[(2 * kp + 1) * DD + d]);
    }
}

// ---------------- dst-CSR build (once per call) ----------------

__global__ void count_kernel(const int* __restrict__ dst,
                             const int* __restrict__ et,
                             int* __restrict__ cnt) {
    int i = blockIdx.x * 256 + threadIdx.x;
    if (i < NE) atomicAdd(&cnt[et[i] * NTILES + (dst[i] >> 7)], 1);
}

__global__ void scan_kernel(const int* __restrict__ cnt, int* __restrict__ off, int n) {
    __shared__ int ts[1024];
    int t = threadIdx.x;
    int v[8];
    int s = 0;
#pragma unroll
    for (int j = 0; j < 8; j++) {
        int idx = t * 8 + j;
        int c = (idx < n) ? cnt[idx] : 0;
        v[j] = s;
        s += c;
    }
    ts[t] = s;
    __syncthreads();
    for (int d = 1; d < 1024; d <<= 1) {
        int add = (t >= d) ? ts[t - d] : 0;
        __syncthreads();
        ts[t] += add;
        __syncthreads();
    }
    int base = (t > 0) ? ts[t - 1] : 0;
#pragma unroll
    for (int j = 0; j < 8; j++) {
        int idx = t * 8 + j;
        if (idx < n) off[idx] = base + v[j];
    }
    if (t == 1023) off[n] = ts[1023];
}

__global__ void fill_kernel(const int* __restrict__ src, const int* __restrict__ dst,
                            const int* __restrict__ et, const int* __restrict__ off,
                            int* __restrict__ cursor, int* __restrict__ ep) {
    int i = blockIdx.x * 256 + threadIdx.x;
    if (i < NE) {
        int d = dst[i];
        int b = et[i] * NTILES + (d >> 7);
        int pos = off[b] + atomicAdd(&cursor[b], 1);
        ep[pos] = (src[i] << 8) | (d & 127);
    }
}

// ---------------- gemm1: sort+register gather -> bf16 LDS -> MFMA z=h@W1+b1, BN stats ----------------

__launch_bounds__(256, 4)
__global__ void gemm1_kernel(const u16* __restrict__ xb,
                             const int* __restrict__ ep, const int* __restrict__ off,
                             const u16* __restrict__ wt1, const float* __restrict__ b1l,
                             const float* __restrict__ rb1l,
                             u16* __restrict__ zb, float* __restrict__ stats) {
    __shared__ u16 hsb[TILE * HROW];      // 18KB bf16 h-tile (then reused for z)
    __shared__ int seS[CAP], seD[CAP];
    __shared__ int shist[TILE], scur[TILE], soff[TILE + 1];
    __shared__ float red[2 * DD];
    int r = blockIdx.y;
    bool root = (r == NR);
    int n0 = blockIdx.x * TILE;
    int tid = threadIdx.x;

    int wv = tid >> 6;
    int l  = tid & 63;
    int lr = l & 15;    // A row / B col / D col
    int lg = l >> 4;    // k-group / D row-group

    // B fragments straight from pre-transposed global Wt (issued early, overlap gather)
    const u16* wtg = wt1 + (size_t)r * DD * DD;
    short8 bfrg[2][4];
#pragma unroll
    for (int ks = 0; ks < 2; ks++)
#pragma unroll
        for (int ct = 0; ct < 4; ct++)
            bfrg[ks][ct] = *(const short8*)&wtg[(ct * 16 + lr) * DD + ks * 32 + lg * 8];

    if (tid < 128) red[tid] = 0.f;

    if (!root) {
        int b = r * NTILES + blockIdx.x;
        int e0 = off[b], e1 = off[b + 1];
        int m = e1 - e0;
        int slot = tid & 127, half = tid >> 7;
        float acc[32];
#pragma unroll
        for (int j = 0; j < 32; j++) acc[j] = 0.f;

        for (int base = 0; base < m; base += CAP) {
            int cnt = min(m - base, CAP);
            if (tid < TILE) shist[tid] = 0;
            __syncthreads();
            for (int i = tid; i < cnt; i += 256) {
                int p = ep[e0 + base + i];
                seS[i] = p;
                atomicAdd(&shist[p & 127], 1);
            }
            __syncthreads();
            if (tid < TILE) soff[tid + 1] = shist[tid];
            if (tid == 0) soff[0] = 0;
            __syncthreads();
            for (int d = 1; d < TILE; d <<= 1) {
                int v = 0;
                if (tid < TILE && tid >= d) v = soff[tid + 1 - d];
                __syncthreads();
                if (tid < TILE && tid >= d) soff[tid + 1] += v;
                __syncthreads();
            }
            if (tid < TILE) scur[tid] = soff[tid];
            __syncthreads();
            for (int i = tid; i < cnt; i += 256) {
                int p = seS[i];
                seD[atomicAdd(&scur[p & 127], 1)] = p;
            }
            __syncthreads();
            int sb = soff[slot], se = soff[slot + 1];
            int e = sb;
            for (; e + 2 <= se; e += 2) {       // 2-edge unroll: 8 loads in flight
                const u16* xr0 = &xb[(size_t)(seD[e] >> 8) * DD + half * 32];
                const u16* xr1 = &xb[(size_t)(seD[e + 1] >> 8) * DD + half * 32];
                uint4 a0 = *(const uint4*)(xr0);      uint4 c0 = *(const uint4*)(xr1);
                uint4 a1 = *(const uint4*)(xr0 + 8);  uint4 c1 = *(const uint4*)(xr1 + 8);
                uint4 a2 = *(const uint4*)(xr0 + 16); uint4 c2 = *(const uint4*)(xr1 + 16);
                uint4 a3 = *(const uint4*)(xr0 + 24); uint4 c3 = *(const uint4*)(xr1 + 24);
                acc8(acc, a0, a1, a2, a3);
                acc8(acc, c0, c1, c2, c3);
            }
            if (e < se) {
                const u16* xr = &xb[(size_t)(seD[e] >> 8) * DD + half * 32];
                acc8(acc, *(const uint4*)(xr), *(const uint4*)(xr + 8),
                     *(const uint4*)(xr + 16), *(const uint4*)(xr + 24));
            }
            __syncthreads();   // protect seS/seD before next chunk restage
        }
        // pack h to bf16, one conflict-free write burst per thread
        u32 pw[16];
#pragma unroll
        for (int j = 0; j < 16; j++) pw[j] = pk(acc[2 * j], acc[2 * j + 1]);
        u16* hrow = &hsb[slot * HROW + half * 32];
        *(uint4*)(hrow)      = make_uint4(pw[0], pw[1], pw[2], pw[3]);
        *(uint4*)(hrow + 8)  = make_uint4(pw[4], pw[5], pw[6], pw[7]);
        *(uint4*)(hrow + 16) = make_uint4(pw[8], pw[9], pw[10], pw[11]);
        *(uint4*)(hrow + 24) = make_uint4(pw[12], pw[13], pw[14], pw[15]);
    } else {
        for (int idx = tid; idx < TILE * 8; idx += 256) {
            int row = idx >> 3, q = idx & 7;
            int n = n0 + row;
            uint4 v = make_uint4(0, 0, 0, 0);
            if (n < NN) v = *(const uint4*)&xb[(size_t)n * DD + q * 8];
            *(uint4*)&hsb[row * HROW + q * 8] = v;
        }
    }
    __syncthreads();

    // ---- MFMA: wave w owns rows 32w..32w+31, all 64 cols ----
    f32x4 dacc[2][4];
#pragma unroll
    for (int rt = 0; rt < 2; rt++)
#pragma unroll
        for (int ct = 0; ct < 4; ct++) dacc[rt][ct] = (f32x4){0.f, 0.f, 0.f, 0.f};

#pragma unroll
    for (int ks = 0; ks < 2; ks++) {
        short8 afr[2];
#pragma unroll
        for (int rt = 0; rt < 2; rt++)
            afr[rt] = *(const short8*)&hsb[(wv * 32 + rt * 16 + lr) * HROW + ks * 32 + lg * 8];
#pragma unroll
        for (int ct = 0; ct < 4; ct++) {
            dacc[0][ct] = __builtin_amdgcn_mfma_f32_16x16x32_bf16(afr[0], bfrg[ks][ct], dacc[0][ct], 0, 0, 0);
            dacc[1][ct] = __builtin_amdgcn_mfma_f32_16x16x32_bf16(afr[1], bfrg[ks][ct], dacc[1][ct], 0, 0, 0);
        }
    }

    // bias + BN stats (per-lane cols 16ct+lr, rows wv*32+rt*16+lg*4+i)
    const float* bvec = root ? rb1l : (b1l + r * DD);
    float bv4[4], s1v[4], s2v[4];
#pragma unroll
    for (int ct = 0; ct < 4; ct++) { bv4[ct] = bvec[16 * ct + lr]; s1v[ct] = 0.f; s2v[ct] = 0.f; }
#pragma unroll
    for (int rt = 0; rt < 2; rt++)
#pragma unroll
        for (int ct = 0; ct < 4; ct++)
#pragma unroll
            for (int i = 0; i < 4; i++) {
                float v = dacc[rt][ct][i] + bv4[ct];
                dacc[rt][ct][i] = v;
                int n = n0 + wv * 32 + rt * 16 + lg * 4 + i;
                if (n < NN) { s1v[ct] += v; s2v[ct] += v * v; }
            }
#pragma unroll
    for (int ct = 0; ct < 4; ct++) {
        float a = s1v[ct], bq = s2v[ct];
        a += __shfl_xor(a, 16); bq += __shfl_xor(bq, 16);
        a += __shfl_xor(a, 32); bq += __shfl_xor(bq, 32);
        if (lg == 0) {
            atomicAdd(&red[16 * ct + lr], a);
            atomicAdd(&red[64 + 16 * ct + lr], bq);
        }
    }
    __syncthreads();   // hsb reads done; red complete

    // scatter z (bf16) into hsb, then coalesced flush
#pragma unroll
    for (int rt = 0; rt < 2; rt++)
#pragma unroll
        for (int ct = 0; ct < 4; ct++)
#pragma unroll
            for (int i = 0; i < 4; i++)
                hsb[(wv * 32 + rt * 16 + lg * 4 + i) * HROW + 16 * ct + lr] = f2b(dacc[rt][ct][i]);
    __syncthreads();

    u16* zout = zb + (size_t)r * NN * DD;
    for (int idx = tid; idx < TILE * 8; idx += 256) {
        int row = idx >> 3, q = idx & 7;
        int n = n0 + row;
        if (n < NN)
            *(uint4*)&zout[(size_t)n * DD + q * 8] = *(const uint4*)&hsb[row * HROW + q * 8];
    }
    if (tid < 64) {
        atomicAdd(&stats[r * DD + tid], red[tid]);
        atomicAdd(&stats[576 + r * DD + tid], red[64 + tid]);
    }
}

// ---------------- finalize: BN affine + fused const bias ----------------

__global__ void finalize_kernel(const float* __restrict__ stats,
                                const float* __restrict__ g1l, const float* __restrict__ be1l,
                                const float* __restrict__ rg1l, const float* __restrict__ rbe1l,
                                const float* __restrict__ b2l, const float* __restrict__ rb2l,
                                const float* __restrict__ biasl,
                                float* __restrict__ affine, float* __restrict__ constd) {
    int t = threadIdx.x;
    if (t < 576) {
        int r = t >> 6, d = t & 63;
        float mean = stats[t] * (1.f / NN);
        float var = fmaxf(stats[576 + t] * (1.f / NN) - mean * mean, 0.f);
        float g  = (r < NR) ? g1l[r * DD + d]  : rg1l[d];
        float be = (r < NR) ? be1l[r * DD + d] : rbe1l[d];
        float sc = g * rsqrtf(var + EPSB);
        affine[t] = sc;
        affine[576 + t] = be - mean * sc;
        if (r == 0) {
            float cd = rb2l[d] + biasl[d];
#pragma unroll
            for (int rr = 0; rr < NR; rr++) cd += b2l[rr * DD + d];
            constd[d] = cd;
        }
    }
}

// ---------------- pass2: MFMA out = sum_r relu(bn(z_r)) @ W2_r + const ----------------

__launch_bounds__(256, 4)
__global__ void pass2_kernel(const u16* __restrict__ zb, const u16* __restrict__ wt2,
                             const float* __restrict__ affine, const float* __restrict__ constd,
                             float* __restrict__ outf, u16* __restrict__ outb,
                             int emit_bf16_relu) {
    __shared__ u16 zsb[TILE * HROW];      // 18KB bf16 activated z-tile (reused for output)
    __shared__ u16 wtb[DD * HROW];        // 9KB Wt[d][k]
    int n0 = blockIdx.x * TILE;
    int tid = threadIdx.x;
    int srow = tid >> 3;          // staging row base (0..31), rows srow+32q
    int sc0 = (tid & 7) * 8;      // staging col base

    int wv = tid >> 6;
    int l  = tid & 63;
    int lr = l & 15;
    int lg = l >> 4;

    f32x4 dacc[2][4];
#pragma unroll
    for (int rt = 0; rt < 2; rt++)
#pragma unroll
        for (int ct = 0; ct < 4; ct++) dacc[rt][ct] = (f32x4){0.f, 0.f, 0.f, 0.f};

    uint4 preA[4], preB[4];
#pragma unroll
    for (int q = 0; q < 4; q++) {
        int n = n0 + srow + 32 * q;
        preA[q] = (n < NN) ? *(const uint4*)&zb[(size_t)n * DD + sc0] : make_uint4(0, 0, 0, 0);
        preB[q] = (n < NN) ? *(const uint4*)&zb[(size_t)NN * DD + (size_t)n * DD + sc0]
                           : make_uint4(0, 0, 0, 0);
    }

#pragma unroll
    for (int r = 0; r < 9; r++) {
        uint4* cur = (r & 1) ? preB : preA;   // compile-time after unroll
        float4 aLo = *(const float4*)&affine[r * DD + sc0];
        float4 aHi = *(const float4*)&affine[r * DD + sc0 + 4];
        float4 cLo = *(const float4*)&affine[576 + r * DD + sc0];
        float4 cHi = *(const float4*)&affine[576 + r * DD + sc0 + 4];
        __syncthreads();   // previous iteration's MFMA frag-reads done
        // write activated tile (bf16) into zsb
#pragma unroll
        for (int q = 0; q < 4; q++) {
            uint4 vv = cur[q];
            float a0 = fmaxf(fmaf(b2f_lo(vv.x), aLo.x, cLo.x), 0.f);
            float a1 = fmaxf(fmaf(b2f_hi(vv.x), aLo.y, cLo.y), 0.f);
            float a2 = fmaxf(fmaf(b2f_lo(vv.y), aLo.z, cLo.z), 0.f);
            float a3 = fmaxf(fmaf(b2f_hi(vv.y), aLo.w, cLo.w), 0.f);
            float a4 = fmaxf(fmaf(b2f_lo(vv.z), aHi.x, cHi.x), 0.f);
            float a5 = fmaxf(fmaf(b2f_hi(vv.z), aHi.y, cHi.y), 0.f);
            float a6 = fmaxf(fmaf(b2f_lo(vv.w), aHi.z, cHi.z), 0.f);
            float a7 = fmaxf(fmaf(b2f_hi(vv.w), aHi.w, cHi.w), 0.f);
            uint4 o = make_uint4(pk(a0, a1), pk(a2, a3), pk(a4, a5), pk(a6, a7));
            *(uint4*)&zsb[(srow + 32 * q) * HROW + sc0] = o;
        }
        // stage W2t: straight coalesced copy from pre-transposed global
        {
            const u32* wsrc = (const u32*)(wt2 + (size_t)r * DD * DD);
            for (int i2 = tid; i2 < DD * 32; i2 += 256) {
                int row = i2 >> 5, q = i2 & 31;
                ((u32*)&wtb[row * HROW])[q] = wsrc[i2];
            }
        }
        __syncthreads();
        // issue z loads for rel r+2 into the buffer just consumed
        if (r + 2 < 9) {
            const u16* zp = zb + (size_t)(r + 2) * NN * DD;
#pragma unroll
            for (int q = 0; q < 4; q++) {
                int n = n0 + srow + 32 * q;
                cur[q] = (n < NN) ? *(const uint4*)&zp[(size_t)n * DD + sc0]
                                  : make_uint4(0, 0, 0, 0);
            }
        }
        // MFMA
#pragma unroll
        for (int ks = 0; ks < 2; ks++) {
            short8 afr[2];
#pragma unroll
            for (int rt = 0; rt < 2; rt++)
                afr[rt] = *(const short8*)&zsb[(wv * 32 + rt * 16 + lr) * HROW + ks * 32 + lg * 8];
#pragma unroll
            for (int ct = 0; ct < 4; ct++) {
                short8 bfr = *(const short8*)&wtb[(ct * 16 + lr) * HROW + ks * 32 + lg * 8];
                dacc[0][ct] = __builtin_amdgcn_mfma_f32_16x16x32_bf16(afr[0], bfr, dacc[0][ct], 0, 0, 0);
                dacc[1][ct] = __builtin_amdgcn_mfma_f32_16x16x32_bf16(afr[1], bfr, dacc[1][ct], 0, 0, 0);
            }
        }
    }

    float cd4[4];
#pragma unroll
    for (int ct = 0; ct < 4; ct++) cd4[ct] = constd[16 * ct + lr];

    if (emit_bf16_relu) {
        __syncthreads();
#pragma unroll
        for (int rt = 0; rt < 2; rt++)
#pragma unroll
            for (int ct = 0; ct < 4; ct++)
#pragma unroll
                for (int i = 0; i < 4; i++) {
                    float v = fmaxf(dacc[rt][ct][i] + cd4[ct], 0.f);
                    zsb[(wv * 32 + rt * 16 + lg * 4 + i) * HROW + 16 * ct + lr] = f2b(v);
                }
        __syncthreads();
        for (int idx = tid; idx < TILE * 8; idx += 256) {
            int row = idx >> 3, q = idx & 7;
            int n = n0 + row;
            if (n < NN)
                *(uint4*)&outb[(size_t)n * DD + q * 8] = *(const uint4*)&zsb[row * HROW + q * 8];
        }
    } else {
        float* zf = (float*)zsb;   // 128 x 34 f32 fits in 18KB
#pragma unroll
        for (int h = 0; h < 2; h++) {
            __syncthreads();
#pragma unroll
            for (int rt = 0; rt < 2; rt++)
#pragma unroll
                for (int cc = 0; cc < 2; cc++) {
                    int ct = 2 * h + cc;
#pragma unroll
                    for (int i = 0; i < 4; i++)
                        zf[(wv * 32 + rt * 16 + lg * 4 + i) * 34 + 16 * cc + lr] =
                            dacc[rt][ct][i] + cd4[ct];
                }
            __syncthreads();
            for (int idx = tid; idx < TILE * 8; idx += 256) {
                int row = idx >> 3, q = idx & 7;
                int n = n0 + row;
                if (n < NN)
                    *(float4*)&outf[(size_t)n * DD + 32 * h + q * 4] =
                        *(const float4*)&zf[row * 34 + q * 4];
            }
        }
    }
}

// ---------------- host ----------------

extern "C" void kernel_launch(void* const* d_in, const int* in_sizes, int n_in,
                              void* d_out, int out_size, void* d_ws, size_t ws_size,
                              hipStream_t stream) {
    (void)in_sizes; (void)n_in; (void)out_size;

    const float* x0   = (const float*)d_in[0];
    const int*   ei   = (const int*)d_in[1];
    const int*   et   = (const int*)d_in[2];
    const float* W1   = (const float*)d_in[3];
    const float* b1   = (const float*)d_in[4];
    const float* g1   = (const float*)d_in[5];
    const float* be1  = (const float*)d_in[6];
    const float* W2   = (const float*)d_in[7];
    const float* b2   = (const float*)d_in[8];
    const float* rW1  = (const float*)d_in[9];
    const float* rb1  = (const float*)d_in[10];
    const float* rg1  = (const float*)d_in[11];
    const float* rbe1 = (const float*)d_in[12];
    const float* rW2  = (const float*)d_in[13];
    const float* rb2  = (const float*)d_in[14];
    const float* bias = (const float*)d_in[15];
    float* out = (float*)d_out;

    char* ws = (char*)d_ws;
    size_t zelems = (size_t)9 * NN * DD;
    u16* zb   = (u16*)ws;                             // 9*NN*DD bf16
    u16* xb   = zb + zelems;                          // NN*DD bf16
    u16* wt1g = xb + (size_t)NN * DD;                 // 2*9*4096 bf16
    u16* wt2g = wt1g + 18 * DD * DD;                  // 2*9*4096 bf16
    float* stats  = (float*)(wt2g + 18 * DD * DD);    // 1152
    float* affine = stats + 1152;                     // 1152
    float* constd = affine + 1152;                    // 64
    int* cnt    = (int*)(constd + 64);                // NBUCKETS
    int* cursor = cnt + NBUCKETS;                     // NBUCKETS
    int* off    = cursor + NBUCKETS;                  // NBUCKETS+1
    int* ep     = off + NBUCKETS + 1;                 // NE

    size_t need = (zelems + (size_t)NN * DD + 36 * DD * DD) * 2
                + (1152 + 1152 + 64) * 4
                + ((size_t)3 * NBUCKETS + 1 + NE) * 4;
    if (ws_size < need) return;

    cvt_kernel<<<(NN * DD / 8 + 255) / 256, 256, 0, stream>>>(x0, xb);
    wt_kernel<<<36, 256, 0, stream>>>(W1, rW1, W2, rW2, wt1g, wt2g);
    hipMemsetAsync(cnt, 0, sizeof(int) * 2 * NBUCKETS, stream);
    count_kernel<<<(NE + 255) / 256, 256, 0, stream>>>(ei + NE, et, cnt);
    scan_kernel<<<1, 1024, 0, stream>>>(cnt, off, NBUCKETS);
    fill_kernel<<<(NE + 255) / 256, 256, 0, stream>>>(ei, ei + NE, et, off, cursor, ep);

    for (int i = 0; i < 2; i++) {
        hipMemsetAsync(stats, 0, sizeof(float) * 1152, stream);
        gemm1_kernel<<<dim3(NTILES, 9), 256, 0, stream>>>(
            xb, ep, off,
            wt1g + (size_t)i * 9 * DD * DD,
            b1 + (size_t)i * NR * DD, rb1 + (size_t)i * DD,
            zb, stats);
        finalize_kernel<<<1, 576, 0, stream>>>(
            stats,
            g1 + (size_t)i * NR * DD, be1 + (size_t)i * NR * DD,
            rg1 + (size_t)i * DD, rbe1 + (size_t)i * DD,
            b2 + (size_t)i * NR * DD, rb2 + (size_t)i * DD, bias + (size_t)i * DD,
            affine, constd);
        pass2_kernel<<<NTILES, 256, 0, stream>>>(
            zb, wt2g + (size_t)i * 9 * DD * DD,
            affine, constd, out, xb, (i == 0) ? 1 : 0);
    }
}